// Round 1
// baseline (602.355 us; speedup 1.0000x reference)
//
#include <hip/hip_runtime.h>
#include <stdint.h>

// Problem constants
#define T_TOK 4096   // B*S
#define DIM   512    // D
#define NEXP  16     // E
#define DHID  2048   // 4*D
#define DSH   1024   // 2*D
#define ROWSCAP 10240  // 2*T + padding slack (sum ceil(c_e/128)*128 <= 10112)
#define MAXTILES 80    // sum ceil(c_e/128) <= 79

typedef __bf16 bf16x8 __attribute__((ext_vector_type(8)));
typedef float  f32x4  __attribute__((ext_vector_type(4)));

__device__ __forceinline__ unsigned short f2b(float f) {
  union { float f; unsigned int u; } un; un.f = f;
  unsigned int u = un.u + 0x7fffu + ((un.u >> 16) & 1u);  // RNE to bf16
  return (unsigned short)(u >> 16);
}

// ---------------- transpose fp32 [R,C] -> bf16 [C,R], batched ----------------
__global__ __launch_bounds__(256) void transpose_cvt(
    const float* __restrict__ src, unsigned short* __restrict__ dst, int R, int C) {
  __shared__ float tile[32][33];
  const int c0 = blockIdx.x * 32, r0 = blockIdx.y * 32;
  const float* s = src + (size_t)blockIdx.z * R * C;
  unsigned short* d = dst + (size_t)blockIdx.z * R * C;
  const int lx = threadIdx.x & 31, ly = threadIdx.x >> 5;  // 32 x 8
#pragma unroll
  for (int i = 0; i < 32; i += 8)
    tile[ly + i][lx] = s[(size_t)(r0 + ly + i) * C + c0 + lx];
  __syncthreads();
#pragma unroll
  for (int i = 0; i < 32; i += 8)
    d[(size_t)(c0 + ly + i) * R + r0 + lx] = f2b(tile[lx][ly + i]);
}

// ---------------- LayerNorm + router + top-2 ----------------
__global__ __launch_bounds__(256) void ln_router_kernel(
    const float* __restrict__ x, const float* __restrict__ g, const float* __restrict__ b,
    const float* __restrict__ rw, const float* __restrict__ rb,
    unsigned short* __restrict__ hb, int* __restrict__ comb_idx, float* __restrict__ comb_w,
    int* __restrict__ counts) {
  const int t = blockIdx.x, tid = threadIdx.x;
  __shared__ float hs[DIM];
  __shared__ float red[4];
  __shared__ float rpart[256];
  const float* xr = x + (size_t)t * DIM;
  const float v0 = xr[tid], v1 = xr[tid + 256];
  float s = v0 + v1;
#pragma unroll
  for (int o = 32; o; o >>= 1) s += __shfl_xor(s, o, 64);
  const int wid = tid >> 6;
  if ((tid & 63) == 0) red[wid] = s;
  __syncthreads();
  const float mu = (red[0] + red[1] + red[2] + red[3]) * (1.f / DIM);
  const float d0 = v0 - mu, d1 = v1 - mu;
  float q = d0 * d0 + d1 * d1;
#pragma unroll
  for (int o = 32; o; o >>= 1) q += __shfl_xor(q, o, 64);
  __syncthreads();
  if ((tid & 63) == 0) red[wid] = q;
  __syncthreads();
  const float var = (red[0] + red[1] + red[2] + red[3]) * (1.f / DIM);
  const float rs = rsqrtf(var + 1e-5f);
  const float h0 = d0 * rs * g[tid] + b[tid];
  const float h1 = d1 * rs * g[tid + 256] + b[tid + 256];
  hs[tid] = h0; hs[tid + 256] = h1;
  hb[(size_t)t * DIM + tid] = f2b(h0);
  hb[(size_t)t * DIM + tid + 256] = f2b(h1);
  __syncthreads();
  // router partials: thread (chunk=tid>>4, e=tid&15) over 32 d's
  const int e = tid & 15, ch = tid >> 4;
  float p = 0.f;
  const float* rwp = rw + e;
#pragma unroll 4
  for (int j = 0; j < 32; ++j) p += hs[ch * 32 + j] * rwp[(ch * 32 + j) * NEXP];
  rpart[ch * 16 + e] = p;
  __syncthreads();
  if (tid < NEXP) {
    float l = rb[tid];
#pragma unroll
    for (int c = 0; c < 16; ++c) l += rpart[c * 16 + tid];
    rpart[tid] = l * (1.f / 0.7f);  // /temperature
  }
  __syncthreads();
  if (tid == 0) {
    float mx = -1e30f;
    for (int i = 0; i < NEXP; ++i) mx = fmaxf(mx, rpart[i]);
    float ge[NEXP]; float se = 0.f;
    for (int i = 0; i < NEXP; ++i) { ge[i] = __expf(rpart[i] - mx); se += ge[i]; }
    const float inv = 1.f / se;
    int i0 = 0; float m0 = -1.f;
    for (int i = 0; i < NEXP; ++i) if (ge[i] > m0) { m0 = ge[i]; i0 = i; }
    int i1 = -1; float m1 = -1.f;
    for (int i = 0; i < NEXP; ++i) if (i != i0 && ge[i] > m1) { m1 = ge[i]; i1 = i; }
    comb_idx[t * 2] = i0; comb_idx[t * 2 + 1] = i1;
    comb_w[t * 2] = m0 * inv; comb_w[t * 2 + 1] = m1 * inv;
    atomicAdd(&counts[i0], 1); atomicAdd(&counts[i1], 1);
  }
}

// ---------------- LayerNorm only (for final ff) ----------------
__global__ __launch_bounds__(256) void ln2_kernel(
    const float* __restrict__ in, const float* __restrict__ g, const float* __restrict__ b,
    unsigned short* __restrict__ ob) {
  const int t = blockIdx.x, tid = threadIdx.x;
  __shared__ float red[4];
  const float* xr = in + (size_t)t * DIM;
  const float v0 = xr[tid], v1 = xr[tid + 256];
  float s = v0 + v1;
#pragma unroll
  for (int o = 32; o; o >>= 1) s += __shfl_xor(s, o, 64);
  const int wid = tid >> 6;
  if ((tid & 63) == 0) red[wid] = s;
  __syncthreads();
  const float mu = (red[0] + red[1] + red[2] + red[3]) * (1.f / DIM);
  const float d0 = v0 - mu, d1 = v1 - mu;
  float q = d0 * d0 + d1 * d1;
#pragma unroll
  for (int o = 32; o; o >>= 1) q += __shfl_xor(q, o, 64);
  __syncthreads();
  if ((tid & 63) == 0) red[wid] = q;
  __syncthreads();
  const float var = (red[0] + red[1] + red[2] + red[3]) * (1.f / DIM);
  const float rs = rsqrtf(var + 1e-5f);
  ob[(size_t)t * DIM + tid]       = f2b(d0 * rs * g[tid] + b[tid]);
  ob[(size_t)t * DIM + tid + 256] = f2b(d1 * rs * g[tid + 256] + b[tid + 256]);
}

// ---------------- plan: padded segment offsets + tile descriptors ----------------
__global__ void plan_kernel(const int* __restrict__ counts, int* __restrict__ offs,
                            int* __restrict__ fill, int* __restrict__ tiledesc) {
  if (threadIdx.x == 0) {
    int run = 0, tix = 0;
    for (int e = 0; e < NEXP; ++e) {
      offs[e] = run;
      const int nt = (counts[e] + 127) >> 7;
      for (int i = 0; i < nt; ++i) { tiledesc[tix * 2] = e; tiledesc[tix * 2 + 1] = run + i * 128; ++tix; }
      run += nt * 128;
    }
    for (; tix < MAXTILES; ++tix) { tiledesc[tix * 2] = -1; tiledesc[tix * 2 + 1] = 0; }
  }
  if (threadIdx.x < NEXP) fill[threadIdx.x] = 0;
}

// ---------------- scatter tokens into expert segments ----------------
__global__ __launch_bounds__(256) void scatter_kernel(
    const int* __restrict__ comb_idx, const float* __restrict__ comb_w,
    const int* __restrict__ offs, int* __restrict__ fill,
    int* __restrict__ token_list, float* __restrict__ tok_w) {
  const int t = blockIdx.x * 256 + threadIdx.x;
#pragma unroll
  for (int j = 0; j < 2; ++j) {
    const int e = comb_idx[t * 2 + j];
    const int p = atomicAdd(&fill[e], 1);
    const int gidx = offs[e] + p;
    token_list[gidx] = t;
    tok_w[gidx] = comb_w[t * 2 + j];
  }
}

// ---------------- bf16 MFMA GEMM, 128x128x32 tile, fused epilogues ----------------
// MODE 0: out = silu(acc + bias) -> bf16 outA[row, N]
// MODE 1: t=token_list[row]; if t>=0: atomicAdd(mix[t, n], tok_w[row]*(acc+bias))
// MODE 2: mix[row, n] += 0.25*(acc+bias)
// MODE 3: out[row, n] = x[row,n] + mix[row,n] + (acc+bias)
template <int MODE, bool EXPERT>
__global__ __launch_bounds__(256) void gemm_kernel(
    const unsigned short* __restrict__ A, int lda,
    const unsigned short* __restrict__ BT,  // bf16 [N, K] (per-expert stride N*K)
    const float* __restrict__ bias, int K, int N,
    const int* __restrict__ tiledesc, const int* __restrict__ token_list,
    const float* __restrict__ tok_w,
    unsigned short* __restrict__ outA, float* __restrict__ mix,
    const float* __restrict__ xres, float* __restrict__ outp) {
  __shared__ unsigned short As[128 * 32];
  __shared__ unsigned short Bs[128 * 32];
  const int tid = threadIdx.x;
  int expert = 0, row0;
  if (EXPERT) {
    expert = tiledesc[blockIdx.y * 2];
    if (expert < 0) return;
    row0 = tiledesc[blockIdx.y * 2 + 1];
  } else {
    row0 = blockIdx.y * 128;
  }
  const int bn = blockIdx.x;
  const unsigned short* Bt = BT + (size_t)expert * N * K + (size_t)bn * 128 * K;
  const float* bp = bias + (EXPERT ? expert * N : 0) + bn * 128;

  // staging assignment: thread -> rows r_a, r_a+64; 8 bf16 at col c8
  const int r_a = tid >> 2;
  const int c8 = (tid & 3) << 3;
  const unsigned short* arow0; const unsigned short* arow1;
  bool z0 = false, z1 = false;
  if (EXPERT && MODE == 0) {
    int t0 = token_list[row0 + r_a];
    int t1 = token_list[row0 + r_a + 64];
    z0 = (t0 < 0); z1 = (t1 < 0);
    if (t0 < 0) t0 = 0;
    if (t1 < 0) t1 = 0;
    arow0 = A + (size_t)t0 * lda + c8;
    arow1 = A + (size_t)t1 * lda + c8;
  } else {
    arow0 = A + (size_t)(row0 + r_a) * lda + c8;
    arow1 = A + (size_t)(row0 + r_a + 64) * lda + c8;
  }
  const unsigned short* brow0 = Bt + (size_t)r_a * K + c8;
  const unsigned short* brow1 = Bt + (size_t)(r_a + 64) * K + c8;

  const int lane = tid & 63, wid = tid >> 6;
  const int wm = wid & 1, wn = wid >> 1;
  const int l15 = lane & 15, qd = lane >> 4;

  f32x4 acc[4][4] = {};

  unsigned short* asd0 = &As[r_a * 32 + c8];
  unsigned short* asd1 = &As[(r_a + 64) * 32 + c8];
  unsigned short* bsd0 = &Bs[r_a * 32 + c8];
  unsigned short* bsd1 = &Bs[(r_a + 64) * 32 + c8];
  const bf16x8* afp = (const bf16x8*)&As[(wm * 64 + l15) * 32 + qd * 8];
  const bf16x8* bfp = (const bf16x8*)&Bs[(wn * 64 + l15) * 32 + qd * 8];

  for (int k0 = 0; k0 < K; k0 += 32) {
    const uint4 zz = make_uint4(0, 0, 0, 0);
    uint4 av0 = z0 ? zz : *(const uint4*)(arow0 + k0);
    uint4 av1 = z1 ? zz : *(const uint4*)(arow1 + k0);
    uint4 bv0 = *(const uint4*)(brow0 + k0);
    uint4 bv1 = *(const uint4*)(brow1 + k0);
    __syncthreads();  // protect previous iteration's LDS reads
    *(uint4*)asd0 = av0;
    *(uint4*)asd1 = av1;
    *(uint4*)bsd0 = bv0;
    *(uint4*)bsd1 = bv1;
    __syncthreads();
    bf16x8 af[4], bq[4];
#pragma unroll
    for (int a = 0; a < 4; ++a) af[a] = afp[a * 64];  // a*16 rows * 32 elems / 8
#pragma unroll
    for (int b2 = 0; b2 < 4; ++b2) bq[b2] = bfp[b2 * 64];
#pragma unroll
    for (int a = 0; a < 4; ++a)
#pragma unroll
      for (int b2 = 0; b2 < 4; ++b2)
        acc[a][b2] = __builtin_amdgcn_mfma_f32_16x16x32_bf16(af[a], bq[b2], acc[a][b2], 0, 0, 0);
  }

  // epilogue: D mapping col=lane&15, row=(lane>>4)*4+reg
  const int mloc = wm * 64 + qd * 4;
  const int nloc = wn * 64 + l15;
#pragma unroll
  for (int b2 = 0; b2 < 4; ++b2) {
    const int n = bn * 128 + nloc + b2 * 16;
    const float bv = bp[nloc + b2 * 16];
#pragma unroll
    for (int a = 0; a < 4; ++a) {
#pragma unroll
      for (int r = 0; r < 4; ++r) {
        const int m = mloc + a * 16 + r;
        const float val = acc[a][b2][r] + bv;
        if (MODE == 0) {
          const float sg = val / (1.f + __expf(-val));
          outA[(size_t)(row0 + m) * N + n] = f2b(sg);
        } else if (MODE == 1) {
          const int tt = token_list[row0 + m];
          if (tt >= 0) atomicAdd(&mix[(size_t)tt * DIM + n], tok_w[row0 + m] * val);
        } else if (MODE == 2) {
          const size_t o = (size_t)(row0 + m) * DIM + n;
          mix[o] += 0.25f * val;
        } else {
          const size_t o = (size_t)(row0 + m) * DIM + n;
          outp[o] = xres[o] + mix[o] + val;
        }
      }
    }
  }
}

extern "C" void kernel_launch(void* const* d_in, const int* in_sizes, int n_in,
                              void* d_out, int out_size, void* d_ws, size_t ws_size,
                              hipStream_t stream) {
  (void)in_sizes; (void)n_in; (void)out_size; (void)ws_size;
  const float* x    = (const float*)d_in[0];
  const float* lng  = (const float*)d_in[1];
  const float* lnb  = (const float*)d_in[2];
  const float* rw   = (const float*)d_in[3];
  const float* rb   = (const float*)d_in[4];
  const float* ew1  = (const float*)d_in[5];
  const float* eb1  = (const float*)d_in[6];
  const float* ew2  = (const float*)d_in[7];
  const float* eb2  = (const float*)d_in[8];
  const float* sw1  = (const float*)d_in[9];
  const float* sb1  = (const float*)d_in[10];
  const float* sw2  = (const float*)d_in[11];
  const float* sb2  = (const float*)d_in[12];
  const float* flng = (const float*)d_in[13];
  const float* flnb = (const float*)d_in[14];
  const float* fw1  = (const float*)d_in[15];
  const float* fb1  = (const float*)d_in[16];
  const float* fw2  = (const float*)d_in[17];
  const float* fb2  = (const float*)d_in[18];
  float* out = (float*)d_out;

  char* ws = (char*)d_ws;
  size_t off = 0;
  auto alloc = [&](size_t bytes) -> void* {
    void* p = ws + off;
    off += (bytes + 255) & ~(size_t)255;
    return p;
  };
  // total ~134 MB of ws
  unsigned short* ew1T = (unsigned short*)alloc((size_t)NEXP * DIM * DHID * 2);
  unsigned short* ew2T = (unsigned short*)alloc((size_t)NEXP * DHID * DIM * 2);
  unsigned short* sw1T = (unsigned short*)alloc((size_t)DIM * DSH * 2);
  unsigned short* sw2T = (unsigned short*)alloc((size_t)DSH * DIM * 2);
  unsigned short* fw1T = (unsigned short*)alloc((size_t)DIM * DHID * 2);
  unsigned short* fw2T = (unsigned short*)alloc((size_t)DHID * DIM * 2);
  unsigned short* hb   = (unsigned short*)alloc((size_t)T_TOK * DIM * 2);
  unsigned short* fhb  = (unsigned short*)alloc((size_t)T_TOK * DIM * 2);
  unsigned short* Abuf = (unsigned short*)alloc((size_t)ROWSCAP * DHID * 2);
  float* mix     = (float*)alloc((size_t)T_TOK * DIM * 4);
  int*   comb_idx = (int*)alloc((size_t)T_TOK * 2 * 4);
  float* comb_w   = (float*)alloc((size_t)T_TOK * 2 * 4);
  int* counts   = (int*)alloc(64);
  int* offs     = (int*)alloc(64);
  int* fill     = (int*)alloc(64);
  int* tiledesc = (int*)alloc(MAXTILES * 2 * 4);
  int*   token_list = (int*)alloc((size_t)ROWSCAP * 4);
  float* tok_w      = (float*)alloc((size_t)ROWSCAP * 4);

  hipMemsetAsync(counts, 0, 64, stream);
  hipMemsetAsync(mix, 0, (size_t)T_TOK * DIM * 4, stream);
  hipMemsetAsync(token_list, 0xFF, (size_t)ROWSCAP * 4, stream);  // -1

  // weight transposes (fp32 [K,N] -> bf16 [N,K])
  transpose_cvt<<<dim3(DHID / 32, DIM / 32, NEXP), 256, 0, stream>>>(ew1, ew1T, DIM, DHID);
  transpose_cvt<<<dim3(DIM / 32, DHID / 32, NEXP), 256, 0, stream>>>(ew2, ew2T, DHID, DIM);
  transpose_cvt<<<dim3(DSH / 32, DIM / 32, 1), 256, 0, stream>>>(sw1, sw1T, DIM, DSH);
  transpose_cvt<<<dim3(DIM / 32, DSH / 32, 1), 256, 0, stream>>>(sw2, sw2T, DSH, DIM);
  transpose_cvt<<<dim3(DHID / 32, DIM / 32, 1), 256, 0, stream>>>(fw1, fw1T, DIM, DHID);
  transpose_cvt<<<dim3(DIM / 32, DHID / 32, 1), 256, 0, stream>>>(fw2, fw2T, DHID, DIM);

  ln_router_kernel<<<T_TOK, 256, 0, stream>>>(x, lng, lnb, rw, rb, hb, comb_idx, comb_w, counts);
  plan_kernel<<<1, 64, 0, stream>>>(counts, offs, fill, tiledesc);
  scatter_kernel<<<T_TOK / 256, 256, 0, stream>>>(comb_idx, comb_w, offs, fill, token_list, tok_w);

  // experts: silu(hg @ W1 + b1) -> Abuf ; (Abuf @ W2 + b2) weighted-atomic into mix
  gemm_kernel<0, true><<<dim3(DHID / 128, MAXTILES), 256, 0, stream>>>(
      hb, DIM, ew1T, eb1, DIM, DHID, tiledesc, token_list, tok_w, Abuf, nullptr, nullptr, nullptr);
  gemm_kernel<1, true><<<dim3(DIM / 128, MAXTILES), 256, 0, stream>>>(
      Abuf, DHID, ew2T, eb2, DHID, DIM, tiledesc, token_list, tok_w, nullptr, mix, nullptr, nullptr);
  // shared expert into mix (Abuf reused)
  gemm_kernel<0, false><<<dim3(DSH / 128, T_TOK / 128), 256, 0, stream>>>(
      hb, DIM, sw1T, sb1, DIM, DSH, nullptr, nullptr, nullptr, Abuf, nullptr, nullptr, nullptr);
  gemm_kernel<2, false><<<dim3(DIM / 128, T_TOK / 128), 256, 0, stream>>>(
      Abuf, DSH, sw2T, sb2, DSH, DIM, nullptr, nullptr, nullptr, nullptr, mix, nullptr, nullptr);
  // final ff block (Abuf reused)
  ln2_kernel<<<T_TOK, 256, 0, stream>>>(mix, flng, flnb, fhb);
  gemm_kernel<0, false><<<dim3(DHID / 128, T_TOK / 128), 256, 0, stream>>>(
      fhb, DIM, fw1T, fb1, DIM, DHID, nullptr, nullptr, nullptr, Abuf, nullptr, nullptr, nullptr);
  gemm_kernel<3, false><<<dim3(DIM / 128, T_TOK / 128), 256, 0, stream>>>(
      Abuf, DHID, fw2T, fb2, DHID, DIM, nullptr, nullptr, nullptr, nullptr, mix, x, out);
}

// Round 2
// 515.008 us; speedup vs baseline: 1.1696x; 1.1696x over previous
//
#include <hip/hip_runtime.h>
#include <stdint.h>

// Problem constants
#define T_TOK 4096   // B*S
#define DIM   512    // D
#define NEXP  16     // E
#define DHID  2048   // 4*D
#define DSH   1024   // 2*D
#define ROWSCAP 10240  // 2*T + padding slack (sum ceil(c_e/128)*128 <= 10112)
#define MAXTILES 80    // sum ceil(c_e/128) <= 79

typedef __bf16 bf16x8 __attribute__((ext_vector_type(8)));
typedef float  f32x4  __attribute__((ext_vector_type(4)));

__device__ __forceinline__ unsigned short f2b(float f) {
  union { float f; unsigned int u; } un; un.f = f;
  unsigned int u = un.u + 0x7fffu + ((un.u >> 16) & 1u);  // RNE to bf16
  return (unsigned short)(u >> 16);
}

__device__ __forceinline__ void async16(void* lds, const void* gp) {
  __builtin_amdgcn_global_load_lds(
      (const __attribute__((address_space(1))) unsigned int*)gp,
      (__attribute__((address_space(3))) unsigned int*)lds, 16, 0, 0);
}

// ---------------- transpose fp32 [R,C] -> bf16 [C,R], batched ----------------
__global__ __launch_bounds__(256) void transpose_cvt(
    const float* __restrict__ src, unsigned short* __restrict__ dst, int R, int C) {
  __shared__ float tile[32][33];
  const int c0 = blockIdx.x * 32, r0 = blockIdx.y * 32;
  const float* s = src + (size_t)blockIdx.z * R * C;
  unsigned short* d = dst + (size_t)blockIdx.z * R * C;
  const int lx = threadIdx.x & 31, ly = threadIdx.x >> 5;  // 32 x 8
#pragma unroll
  for (int i = 0; i < 32; i += 8)
    tile[ly + i][lx] = s[(size_t)(r0 + ly + i) * C + c0 + lx];
  __syncthreads();
#pragma unroll
  for (int i = 0; i < 32; i += 8)
    d[(size_t)(c0 + ly + i) * R + r0 + lx] = f2b(tile[lx][ly + i]);
}

// ---------------- LayerNorm + router + top-2 : wave-per-token ----------------
__global__ __launch_bounds__(256) void ln_router_kernel(
    const float* __restrict__ x, const float* __restrict__ g, const float* __restrict__ b,
    const float* __restrict__ rw, const float* __restrict__ rb,
    unsigned short* __restrict__ hbuf, int* __restrict__ comb_idx, float* __restrict__ comb_w,
    int* __restrict__ counts) {
  const int wid = threadIdx.x >> 6, lane = threadIdx.x & 63;
  const int t = blockIdx.x * 4 + wid;
  __shared__ int hist[NEXP];
  if (threadIdx.x < NEXP) hist[threadIdx.x] = 0;
  __syncthreads();

  const float4* xr = (const float4*)(x + (size_t)t * DIM);
  const float4 va = xr[lane], vb = xr[lane + 64];
  float s = (va.x + va.y) + (va.z + va.w) + ((vb.x + vb.y) + (vb.z + vb.w));
#pragma unroll
  for (int o = 32; o; o >>= 1) s += __shfl_xor(s, o, 64);
  const float mu = s * (1.f / DIM);
  float da[4] = {va.x - mu, va.y - mu, va.z - mu, va.w - mu};
  float db[4] = {vb.x - mu, vb.y - mu, vb.z - mu, vb.w - mu};
  float q = (da[0]*da[0] + da[1]*da[1]) + (da[2]*da[2] + da[3]*da[3]) +
            ((db[0]*db[0] + db[1]*db[1]) + (db[2]*db[2] + db[3]*db[3]));
#pragma unroll
  for (int o = 32; o; o >>= 1) q += __shfl_xor(q, o, 64);
  const float rs = rsqrtf(q * (1.f / DIM) + 1e-5f);
  const float4 ga = ((const float4*)g)[lane], gb4 = ((const float4*)g)[lane + 64];
  const float4 ba = ((const float4*)b)[lane], bb4 = ((const float4*)b)[lane + 64];
  float ha[4], hbv[4];
  ha[0] = da[0] * rs * ga.x + ba.x;  ha[1] = da[1] * rs * ga.y + ba.y;
  ha[2] = da[2] * rs * ga.z + ba.z;  ha[3] = da[3] * rs * ga.w + ba.w;
  hbv[0] = db[0] * rs * gb4.x + bb4.x;  hbv[1] = db[1] * rs * gb4.y + bb4.y;
  hbv[2] = db[2] * rs * gb4.z + bb4.z;  hbv[3] = db[3] * rs * gb4.w + bb4.w;
  ushort4 ua = {f2b(ha[0]), f2b(ha[1]), f2b(ha[2]), f2b(ha[3])};
  ushort4 ub = {f2b(hbv[0]), f2b(hbv[1]), f2b(hbv[2]), f2b(hbv[3])};
  ((ushort4*)(hbuf + (size_t)t * DIM))[lane] = ua;
  ((ushort4*)(hbuf + (size_t)t * DIM))[lane + 64] = ub;

  // router partials: lane owns cols {4*lane..+3} and {256+4*lane..+3}
  float p[NEXP];
#pragma unroll
  for (int e = 0; e < NEXP; ++e) p[e] = 0.f;
  const int c0 = lane * 4;
#pragma unroll
  for (int half = 0; half < 2; ++half) {
#pragma unroll
    for (int j = 0; j < 4; ++j) {
      const int col = half * 256 + c0 + j;
      const float hv = half ? hbv[j] : ha[j];
      const float4* wr = (const float4*)(rw + (size_t)col * NEXP);
#pragma unroll
      for (int qq = 0; qq < 4; ++qq) {
        const float4 w = wr[qq];
        p[qq * 4 + 0] += hv * w.x;  p[qq * 4 + 1] += hv * w.y;
        p[qq * 4 + 2] += hv * w.z;  p[qq * 4 + 3] += hv * w.w;
      }
    }
  }
  // butterfly reduce each of 16 partials across the wave
#pragma unroll
  for (int o = 32; o; o >>= 1) {
#pragma unroll
    for (int e = 0; e < NEXP; ++e) p[e] += __shfl_xor(p[e], o, 64);
  }
  // softmax + top-2 (redundant in all lanes; stays in registers)
  float mx = -1e30f;
#pragma unroll
  for (int e = 0; e < NEXP; ++e) {
    p[e] = (p[e] + rb[e]) * (1.f / 0.7f);
    mx = fmaxf(mx, p[e]);
  }
  float ge[NEXP], se = 0.f;
#pragma unroll
  for (int e = 0; e < NEXP; ++e) { ge[e] = __expf(p[e] - mx); se += ge[e]; }
  const float inv = 1.f / se;
  int i0 = 0; float m0 = ge[0];
#pragma unroll
  for (int e = 1; e < NEXP; ++e) if (ge[e] > m0) { m0 = ge[e]; i0 = e; }
  int i1 = -1; float m1 = -1.f;
#pragma unroll
  for (int e = 0; e < NEXP; ++e) if (e != i0 && ge[e] > m1) { m1 = ge[e]; i1 = e; }
  if (lane == 0) {
    comb_idx[t * 2] = i0; comb_idx[t * 2 + 1] = i1;
    comb_w[t * 2] = m0 * inv; comb_w[t * 2 + 1] = m1 * inv;
    atomicAdd(&hist[i0], 1); atomicAdd(&hist[i1], 1);
  }
  __syncthreads();
  if (threadIdx.x < NEXP) {
    const int c = hist[threadIdx.x];
    if (c) atomicAdd(&counts[threadIdx.x], c);
  }
}

// ---------------- LayerNorm only (final ff) : wave-per-token, no barriers ----------------
__global__ __launch_bounds__(256) void ln2_kernel(
    const float* __restrict__ in, const float* __restrict__ g, const float* __restrict__ b,
    unsigned short* __restrict__ ob) {
  const int wid = threadIdx.x >> 6, lane = threadIdx.x & 63;
  const int t = blockIdx.x * 4 + wid;
  const float4* xr = (const float4*)(in + (size_t)t * DIM);
  const float4 va = xr[lane], vb = xr[lane + 64];
  float s = (va.x + va.y) + (va.z + va.w) + ((vb.x + vb.y) + (vb.z + vb.w));
#pragma unroll
  for (int o = 32; o; o >>= 1) s += __shfl_xor(s, o, 64);
  const float mu = s * (1.f / DIM);
  float da[4] = {va.x - mu, va.y - mu, va.z - mu, va.w - mu};
  float db[4] = {vb.x - mu, vb.y - mu, vb.z - mu, vb.w - mu};
  float q = (da[0]*da[0] + da[1]*da[1]) + (da[2]*da[2] + da[3]*da[3]) +
            ((db[0]*db[0] + db[1]*db[1]) + (db[2]*db[2] + db[3]*db[3]));
#pragma unroll
  for (int o = 32; o; o >>= 1) q += __shfl_xor(q, o, 64);
  const float rs = rsqrtf(q * (1.f / DIM) + 1e-5f);
  const float4 ga = ((const float4*)g)[lane], gb4 = ((const float4*)g)[lane + 64];
  const float4 ba = ((const float4*)b)[lane], bb4 = ((const float4*)b)[lane + 64];
  ushort4 ua = {f2b(da[0] * rs * ga.x + ba.x), f2b(da[1] * rs * ga.y + ba.y),
                f2b(da[2] * rs * ga.z + ba.z), f2b(da[3] * rs * ga.w + ba.w)};
  ushort4 ub = {f2b(db[0] * rs * gb4.x + bb4.x), f2b(db[1] * rs * gb4.y + bb4.y),
                f2b(db[2] * rs * gb4.z + bb4.z), f2b(db[3] * rs * gb4.w + bb4.w)};
  ((ushort4*)(ob + (size_t)t * DIM))[lane] = ua;
  ((ushort4*)(ob + (size_t)t * DIM))[lane + 64] = ub;
}

// ---------------- plan: padded segment offsets + tile descriptors ----------------
__global__ void plan_kernel(const int* __restrict__ counts, int* __restrict__ offs,
                            int* __restrict__ fill, int* __restrict__ tiledesc) {
  if (threadIdx.x == 0) {
    int run = 0, tix = 0;
    for (int e = 0; e < NEXP; ++e) {
      offs[e] = run;
      const int nt = (counts[e] + 127) >> 7;
      for (int i = 0; i < nt; ++i) { tiledesc[tix * 2] = e; tiledesc[tix * 2 + 1] = run + i * 128; ++tix; }
      run += nt * 128;
    }
    for (; tix < MAXTILES; ++tix) { tiledesc[tix * 2] = -1; tiledesc[tix * 2 + 1] = 0; }
  }
  if (threadIdx.x < NEXP) fill[threadIdx.x] = 0;
}

// ---------------- scatter tokens into expert segments ----------------
__global__ __launch_bounds__(256) void scatter_kernel(
    const int* __restrict__ comb_idx, const float* __restrict__ comb_w,
    const int* __restrict__ offs, int* __restrict__ fill,
    int* __restrict__ token_list, float* __restrict__ tok_w) {
  const int t = blockIdx.x * 256 + threadIdx.x;
#pragma unroll
  for (int j = 0; j < 2; ++j) {
    const int e = comb_idx[t * 2 + j];
    const int p = atomicAdd(&fill[e], 1);
    const int gidx = offs[e] + p;
    token_list[gidx] = t;
    tok_w[gidx] = comb_w[t * 2 + j];
  }
}

// ---------------- bf16 MFMA GEMM, 128x128x32 tile, async LDS staging ----------------
// MODE 0: out = silu(acc + bias) -> bf16 outA[row, N]
// MODE 1: t=token_list[row]; if t>=0: atomicAdd(mix[t, n], tok_w[row]*(acc+bias))
// MODE 2: mix[row, n] += 0.25*(acc+bias)
// MODE 3: out[row, n] = x[row,n] + mix[row,n] + (acc+bias)
template <int MODE, bool EXPERT>
__global__ __launch_bounds__(256) void gemm_kernel(
    const unsigned short* __restrict__ A, int lda,
    const unsigned short* __restrict__ BT,  // bf16 [N, K] (per-expert stride N*K)
    const float* __restrict__ bias, int K, int N,
    const int* __restrict__ tiledesc, const int* __restrict__ token_list,
    const float* __restrict__ tok_w,
    unsigned short* __restrict__ outA, float* __restrict__ mix,
    const float* __restrict__ xres, float* __restrict__ outp) {
  __shared__ unsigned short As[128 * 32];
  __shared__ unsigned short Bs[128 * 32];
  const int tid = threadIdx.x;
  int expert = 0, row0;
  if (EXPERT) {
    expert = tiledesc[blockIdx.y * 2];
    if (expert < 0) return;
    row0 = tiledesc[blockIdx.y * 2 + 1];
  } else {
    row0 = blockIdx.y * 128;
  }
  const int bn = blockIdx.x;
  const unsigned short* Bt = BT + (size_t)expert * N * K + (size_t)bn * 128 * K;
  const float* bp = bias + (EXPERT ? expert * N : 0) + bn * 128;

  // staging assignment: thread tid -> LDS byte offset tid*16 (lane-contiguous per wave)
  const int r_a = tid >> 2;
  const int c8 = (tid & 3) << 3;
  const unsigned short* arow0; const unsigned short* arow1;
  if (EXPERT && MODE == 0) {
    // padded rows (token_list<0) just load row 0: finite garbage, discarded downstream
    int t0 = token_list[row0 + r_a];       if (t0 < 0) t0 = 0;
    int t1 = token_list[row0 + r_a + 64];  if (t1 < 0) t1 = 0;
    arow0 = A + (size_t)t0 * lda + c8;
    arow1 = A + (size_t)t1 * lda + c8;
  } else {
    arow0 = A + (size_t)(row0 + r_a) * lda + c8;
    arow1 = A + (size_t)(row0 + r_a + 64) * lda + c8;
  }
  const unsigned short* brow0 = Bt + (size_t)r_a * K + c8;
  const unsigned short* brow1 = Bt + (size_t)(r_a + 64) * K + c8;

  const int lane = tid & 63, wid = tid >> 6;
  const int wm = wid & 1, wn = wid >> 1;
  const int l15 = lane & 15, qd = lane >> 4;

  // wave-uniform LDS bases for async staging (dest = base + lane*16B)
  char* asb0 = (char*)As + wid * 1024;
  char* asb1 = (char*)As + 4096 + wid * 1024;
  char* bsb0 = (char*)Bs + wid * 1024;
  char* bsb1 = (char*)Bs + 4096 + wid * 1024;

  f32x4 acc[4][4] = {};
  const bf16x8* afp = (const bf16x8*)&As[(wm * 64 + l15) * 32 + qd * 8];
  const bf16x8* bfp = (const bf16x8*)&Bs[(wn * 64 + l15) * 32 + qd * 8];

  for (int k0 = 0; k0 < K; k0 += 32) {
    __syncthreads();  // previous iteration's LDS reads complete
    async16(asb0, arow0 + k0);
    async16(asb1, arow1 + k0);
    async16(bsb0, brow0 + k0);
    async16(bsb1, brow1 + k0);
    __syncthreads();  // barrier drains vmcnt -> staged data visible
    bf16x8 af[4], bq[4];
#pragma unroll
    for (int a = 0; a < 4; ++a) af[a] = afp[a * 64];
#pragma unroll
    for (int b2 = 0; b2 < 4; ++b2) bq[b2] = bfp[b2 * 64];
#pragma unroll
    for (int a = 0; a < 4; ++a)
#pragma unroll
      for (int b2 = 0; b2 < 4; ++b2)
        acc[a][b2] = __builtin_amdgcn_mfma_f32_16x16x32_bf16(af[a], bq[b2], acc[a][b2], 0, 0, 0);
  }

  // epilogue: D mapping col=lane&15, row=(lane>>4)*4+reg
  const int mloc = wm * 64 + qd * 4;
  const int nloc = wn * 64 + l15;
#pragma unroll
  for (int b2 = 0; b2 < 4; ++b2) {
    const int n = bn * 128 + nloc + b2 * 16;
    const float bv = bp[nloc + b2 * 16];
#pragma unroll
    for (int a = 0; a < 4; ++a) {
#pragma unroll
      for (int r = 0; r < 4; ++r) {
        const int m = mloc + a * 16 + r;
        const float val = acc[a][b2][r] + bv;
        if (MODE == 0) {
          const float sg = val / (1.f + __expf(-val));
          outA[(size_t)(row0 + m) * N + n] = f2b(sg);
        } else if (MODE == 1) {
          const int tt = token_list[row0 + m];
          if (tt >= 0) atomicAdd(&mix[(size_t)tt * DIM + n], tok_w[row0 + m] * val);
        } else if (MODE == 2) {
          const size_t o = (size_t)(row0 + m) * DIM + n;
          mix[o] += 0.25f * val;
        } else {
          const size_t o = (size_t)(row0 + m) * DIM + n;
          outp[o] = xres[o] + mix[o] + val;
        }
      }
    }
  }
}

extern "C" void kernel_launch(void* const* d_in, const int* in_sizes, int n_in,
                              void* d_out, int out_size, void* d_ws, size_t ws_size,
                              hipStream_t stream) {
  (void)in_sizes; (void)n_in; (void)out_size; (void)ws_size;
  const float* x    = (const float*)d_in[0];
  const float* lng  = (const float*)d_in[1];
  const float* lnb  = (const float*)d_in[2];
  const float* rw   = (const float*)d_in[3];
  const float* rb   = (const float*)d_in[4];
  const float* ew1  = (const float*)d_in[5];
  const float* eb1  = (const float*)d_in[6];
  const float* ew2  = (const float*)d_in[7];
  const float* eb2  = (const float*)d_in[8];
  const float* sw1  = (const float*)d_in[9];
  const float* sb1  = (const float*)d_in[10];
  const float* sw2  = (const float*)d_in[11];
  const float* sb2  = (const float*)d_in[12];
  const float* flng = (const float*)d_in[13];
  const float* flnb = (const float*)d_in[14];
  const float* fw1  = (const float*)d_in[15];
  const float* fb1  = (const float*)d_in[16];
  const float* fw2  = (const float*)d_in[17];
  const float* fb2  = (const float*)d_in[18];
  float* out = (float*)d_out;

  char* ws = (char*)d_ws;
  size_t off = 0;
  auto alloc = [&](size_t bytes) -> void* {
    void* p = ws + off;
    off += (bytes + 255) & ~(size_t)255;
    return p;
  };
  unsigned short* ew1T = (unsigned short*)alloc((size_t)NEXP * DIM * DHID * 2);
  unsigned short* ew2T = (unsigned short*)alloc((size_t)NEXP * DHID * DIM * 2);
  unsigned short* sw1T = (unsigned short*)alloc((size_t)DIM * DSH * 2);
  unsigned short* sw2T = (unsigned short*)alloc((size_t)DSH * DIM * 2);
  unsigned short* fw1T = (unsigned short*)alloc((size_t)DIM * DHID * 2);
  unsigned short* fw2T = (unsigned short*)alloc((size_t)DHID * DIM * 2);
  unsigned short* hb   = (unsigned short*)alloc((size_t)T_TOK * DIM * 2);
  unsigned short* fhb  = (unsigned short*)alloc((size_t)T_TOK * DIM * 2);
  unsigned short* Abuf = (unsigned short*)alloc((size_t)ROWSCAP * DHID * 2);
  float* mix     = (float*)alloc((size_t)T_TOK * DIM * 4);
  int*   comb_idx = (int*)alloc((size_t)T_TOK * 2 * 4);
  float* comb_w   = (float*)alloc((size_t)T_TOK * 2 * 4);
  int* counts   = (int*)alloc(64);
  int* offs     = (int*)alloc(64);
  int* fill     = (int*)alloc(64);
  int* tiledesc = (int*)alloc(MAXTILES * 2 * 4);
  int*   token_list = (int*)alloc((size_t)ROWSCAP * 4);
  float* tok_w      = (float*)alloc((size_t)ROWSCAP * 4);

  hipMemsetAsync(counts, 0, 64, stream);
  hipMemsetAsync(mix, 0, (size_t)T_TOK * DIM * 4, stream);
  hipMemsetAsync(token_list, 0xFF, (size_t)ROWSCAP * 4, stream);  // -1

  // weight transposes (fp32 [K,N] -> bf16 [N,K])
  transpose_cvt<<<dim3(DHID / 32, DIM / 32, NEXP), 256, 0, stream>>>(ew1, ew1T, DIM, DHID);
  transpose_cvt<<<dim3(DIM / 32, DHID / 32, NEXP), 256, 0, stream>>>(ew2, ew2T, DHID, DIM);
  transpose_cvt<<<dim3(DSH / 32, DIM / 32, 1), 256, 0, stream>>>(sw1, sw1T, DIM, DSH);
  transpose_cvt<<<dim3(DIM / 32, DSH / 32, 1), 256, 0, stream>>>(sw2, sw2T, DSH, DIM);
  transpose_cvt<<<dim3(DHID / 32, DIM / 32, 1), 256, 0, stream>>>(fw1, fw1T, DIM, DHID);
  transpose_cvt<<<dim3(DIM / 32, DHID / 32, 1), 256, 0, stream>>>(fw2, fw2T, DHID, DIM);

  ln_router_kernel<<<T_TOK / 4, 256, 0, stream>>>(x, lng, lnb, rw, rb, hb, comb_idx, comb_w, counts);
  plan_kernel<<<1, 64, 0, stream>>>(counts, offs, fill, tiledesc);
  scatter_kernel<<<T_TOK / 256, 256, 0, stream>>>(comb_idx, comb_w, offs, fill, token_list, tok_w);

  // experts: silu(hg @ W1 + b1) -> Abuf ; (Abuf @ W2 + b2) weighted-atomic into mix
  gemm_kernel<0, true><<<dim3(DHID / 128, MAXTILES), 256, 0, stream>>>(
      hb, DIM, ew1T, eb1, DIM, DHID, tiledesc, token_list, tok_w, Abuf, nullptr, nullptr, nullptr);
  gemm_kernel<1, true><<<dim3(DIM / 128, MAXTILES), 256, 0, stream>>>(
      Abuf, DHID, ew2T, eb2, DHID, DIM, tiledesc, token_list, tok_w, nullptr, mix, nullptr, nullptr);
  // shared expert into mix (Abuf reused)
  gemm_kernel<0, false><<<dim3(DSH / 128, T_TOK / 128), 256, 0, stream>>>(
      hb, DIM, sw1T, sb1, DIM, DSH, nullptr, nullptr, nullptr, Abuf, nullptr, nullptr, nullptr);
  gemm_kernel<2, false><<<dim3(DIM / 128, T_TOK / 128), 256, 0, stream>>>(
      Abuf, DSH, sw2T, sb2, DSH, DIM, nullptr, nullptr, nullptr, nullptr, mix, nullptr, nullptr);
  // final ff block (Abuf reused)
  ln2_kernel<<<T_TOK / 4, 256, 0, stream>>>(mix, flng, flnb, fhb);
  gemm_kernel<0, false><<<dim3(DHID / 128, T_TOK / 128), 256, 0, stream>>>(
      fhb, DIM, fw1T, fb1, DIM, DHID, nullptr, nullptr, nullptr, Abuf, nullptr, nullptr, nullptr);
  gemm_kernel<3, false><<<dim3(DIM / 128, T_TOK / 128), 256, 0, stream>>>(
      Abuf, DHID, fw2T, fb2, DHID, DIM, nullptr, nullptr, nullptr, nullptr, mix, x, out);
}

// Round 3
// 479.217 us; speedup vs baseline: 1.2570x; 1.0747x over previous
//
#include <hip/hip_runtime.h>
#include <stdint.h>

// Problem constants
#define T_TOK 4096   // B*S
#define DIM   512    // D
#define NEXP  16     // E
#define DHID  2048   // 4*D
#define DSH   1024   // 2*D
#define ROWSCAP 10240  // 2*T + padding slack (sum ceil(c_e/128)*128 <= 10112)
#define MAXTILES 80    // sum ceil(c_e/128) <= 79

typedef __bf16 bf16x8 __attribute__((ext_vector_type(8)));
typedef float  f32x4  __attribute__((ext_vector_type(4)));

__device__ __forceinline__ unsigned short f2b(float f) {
  union { float f; unsigned int u; } un; un.f = f;
  unsigned int u = un.u + 0x7fffu + ((un.u >> 16) & 1u);  // RNE to bf16
  return (unsigned short)(u >> 16);
}
__device__ __forceinline__ float b2f(unsigned short u) {
  union { unsigned int u; float f; } un; un.u = ((unsigned int)u) << 16; return un.f;
}

__device__ __forceinline__ void async16(void* lds, const void* gp) {
  __builtin_amdgcn_global_load_lds(
      (const __attribute__((address_space(1))) unsigned int*)gp,
      (__attribute__((address_space(3))) unsigned int*)lds, 16, 0, 0);
}

// ------------- all weight transposes fp32 [R,C] -> bf16 [C,R] in ONE dispatch -------------
__global__ __launch_bounds__(256) void transpose_all(
    const float* __restrict__ ew1, const float* __restrict__ ew2,
    const float* __restrict__ sw1, const float* __restrict__ sw2,
    const float* __restrict__ fw1, const float* __restrict__ fw2,
    unsigned short* __restrict__ ew1T, unsigned short* __restrict__ ew2T,
    unsigned short* __restrict__ sw1T, unsigned short* __restrict__ sw2T,
    unsigned short* __restrict__ fw1T, unsigned short* __restrict__ fw2T) {
  __shared__ float tile[32][33];
  int id = blockIdx.x;
  const float* s; unsigned short* d; int R, C, t, sh;
  if (id < 16384)      { int b = id >> 10; t = id & 1023; R = 512;  C = 2048; sh = 6;
                         s = ew1 + (size_t)b * R * C; d = ew1T + (size_t)b * R * C; }
  else if (id < 32768) { id -= 16384; int b = id >> 10; t = id & 1023; R = 2048; C = 512; sh = 4;
                         s = ew2 + (size_t)b * R * C; d = ew2T + (size_t)b * R * C; }
  else if (id < 33280) { t = id - 32768; R = 512;  C = 1024; sh = 5; s = sw1; d = sw1T; }
  else if (id < 33792) { t = id - 33280; R = 1024; C = 512;  sh = 4; s = sw2; d = sw2T; }
  else if (id < 34816) { t = id - 33792; R = 512;  C = 2048; sh = 6; s = fw1; d = fw1T; }
  else                 { t = id - 34816; R = 2048; C = 512;  sh = 4; s = fw2; d = fw2T; }
  const int tx = t & ((1 << sh) - 1), ty = t >> sh;
  const int c0 = tx * 32, r0 = ty * 32;
  const int lx = threadIdx.x & 31, ly = threadIdx.x >> 5;  // 32 x 8
#pragma unroll
  for (int i = 0; i < 32; i += 8)
    tile[ly + i][lx] = s[(size_t)(r0 + ly + i) * C + c0 + lx];
  __syncthreads();
#pragma unroll
  for (int i = 0; i < 32; i += 8)
    d[(size_t)(c0 + ly + i) * R + r0 + lx] = f2b(tile[lx][ly + i]);
}

// ---------------- LayerNorm + router + top-2 : wave-per-token ----------------
__global__ __launch_bounds__(256) void ln_router_kernel(
    const float* __restrict__ x, const float* __restrict__ g, const float* __restrict__ b,
    const float* __restrict__ rw, const float* __restrict__ rb,
    unsigned short* __restrict__ hbuf, int* __restrict__ comb_idx, float* __restrict__ comb_w,
    int* __restrict__ counts) {
  const int wid = threadIdx.x >> 6, lane = threadIdx.x & 63;
  const int t = blockIdx.x * 4 + wid;
  __shared__ int hist[NEXP];
  if (threadIdx.x < NEXP) hist[threadIdx.x] = 0;
  __syncthreads();

  const float4* xr = (const float4*)(x + (size_t)t * DIM);
  const float4 va = xr[lane], vb = xr[lane + 64];
  float s = (va.x + va.y) + (va.z + va.w) + ((vb.x + vb.y) + (vb.z + vb.w));
#pragma unroll
  for (int o = 32; o; o >>= 1) s += __shfl_xor(s, o, 64);
  const float mu = s * (1.f / DIM);
  float da[4] = {va.x - mu, va.y - mu, va.z - mu, va.w - mu};
  float db[4] = {vb.x - mu, vb.y - mu, vb.z - mu, vb.w - mu};
  float q = (da[0]*da[0] + da[1]*da[1]) + (da[2]*da[2] + da[3]*da[3]) +
            ((db[0]*db[0] + db[1]*db[1]) + (db[2]*db[2] + db[3]*db[3]));
#pragma unroll
  for (int o = 32; o; o >>= 1) q += __shfl_xor(q, o, 64);
  const float rs = rsqrtf(q * (1.f / DIM) + 1e-5f);
  const float4 ga = ((const float4*)g)[lane], gb4 = ((const float4*)g)[lane + 64];
  const float4 ba = ((const float4*)b)[lane], bb4 = ((const float4*)b)[lane + 64];
  float ha[4], hbv[4];
  ha[0] = da[0] * rs * ga.x + ba.x;  ha[1] = da[1] * rs * ga.y + ba.y;
  ha[2] = da[2] * rs * ga.z + ba.z;  ha[3] = da[3] * rs * ga.w + ba.w;
  hbv[0] = db[0] * rs * gb4.x + bb4.x;  hbv[1] = db[1] * rs * gb4.y + bb4.y;
  hbv[2] = db[2] * rs * gb4.z + bb4.z;  hbv[3] = db[3] * rs * gb4.w + bb4.w;
  ushort4 ua = {f2b(ha[0]), f2b(ha[1]), f2b(ha[2]), f2b(ha[3])};
  ushort4 ub = {f2b(hbv[0]), f2b(hbv[1]), f2b(hbv[2]), f2b(hbv[3])};
  ((ushort4*)(hbuf + (size_t)t * DIM))[lane] = ua;
  ((ushort4*)(hbuf + (size_t)t * DIM))[lane + 64] = ub;

  // router partials: lane owns cols {4*lane..+3} and {256+4*lane..+3}
  float p[NEXP];
#pragma unroll
  for (int e = 0; e < NEXP; ++e) p[e] = 0.f;
  const int c0 = lane * 4;
#pragma unroll
  for (int half = 0; half < 2; ++half) {
#pragma unroll
    for (int j = 0; j < 4; ++j) {
      const int col = half * 256 + c0 + j;
      const float hv = half ? hbv[j] : ha[j];
      const float4* wr = (const float4*)(rw + (size_t)col * NEXP);
#pragma unroll
      for (int qq = 0; qq < 4; ++qq) {
        const float4 w = wr[qq];
        p[qq * 4 + 0] += hv * w.x;  p[qq * 4 + 1] += hv * w.y;
        p[qq * 4 + 2] += hv * w.z;  p[qq * 4 + 3] += hv * w.w;
      }
    }
  }
#pragma unroll
  for (int o = 32; o; o >>= 1) {
#pragma unroll
    for (int e = 0; e < NEXP; ++e) p[e] += __shfl_xor(p[e], o, 64);
  }
  float mx = -1e30f;
#pragma unroll
  for (int e = 0; e < NEXP; ++e) {
    p[e] = (p[e] + rb[e]) * (1.f / 0.7f);
    mx = fmaxf(mx, p[e]);
  }
  float ge[NEXP], se = 0.f;
#pragma unroll
  for (int e = 0; e < NEXP; ++e) { ge[e] = __expf(p[e] - mx); se += ge[e]; }
  const float inv = 1.f / se;
  int i0 = 0; float m0 = ge[0];
#pragma unroll
  for (int e = 1; e < NEXP; ++e) if (ge[e] > m0) { m0 = ge[e]; i0 = e; }
  int i1 = -1; float m1 = -1.f;
#pragma unroll
  for (int e = 0; e < NEXP; ++e) if (e != i0 && ge[e] > m1) { m1 = ge[e]; i1 = e; }
  if (lane == 0) {
    comb_idx[t * 2] = i0; comb_idx[t * 2 + 1] = i1;
    comb_w[t * 2] = m0 * inv; comb_w[t * 2 + 1] = m1 * inv;
    atomicAdd(&hist[i0], 1); atomicAdd(&hist[i1], 1);
  }
  __syncthreads();
  if (threadIdx.x < NEXP) {
    const int c = hist[threadIdx.x];
    if (c) atomicAdd(&counts[threadIdx.x], c);
  }
}

// ---------------- plan: padded segment offsets + tile descriptors ----------------
__global__ void plan_kernel(const int* __restrict__ counts, int* __restrict__ offs,
                            int* __restrict__ fill, int* __restrict__ tiledesc) {
  if (threadIdx.x == 0) {
    int run = 0, tix = 0;
    for (int e = 0; e < NEXP; ++e) {
      offs[e] = run;
      const int nt = (counts[e] + 127) >> 7;
      for (int i = 0; i < nt; ++i) { tiledesc[tix * 2] = e; tiledesc[tix * 2 + 1] = run + i * 128; ++tix; }
      run += nt * 128;
    }
    for (; tix < MAXTILES; ++tix) { tiledesc[tix * 2] = -1; tiledesc[tix * 2 + 1] = 0; }
  }
  if (threadIdx.x < NEXP) fill[threadIdx.x] = 0;
}

// ---------------- scatter tokens into expert segments (records slots) ----------------
__global__ __launch_bounds__(256) void scatter_kernel(
    const int* __restrict__ comb_idx, const float* __restrict__ comb_w,
    const int* __restrict__ offs, int* __restrict__ fill,
    int* __restrict__ token_list, float* __restrict__ tok_w, int* __restrict__ slots) {
  const int t = blockIdx.x * 256 + threadIdx.x;
#pragma unroll
  for (int j = 0; j < 2; ++j) {
    const int e = comb_idx[t * 2 + j];
    const int p = atomicAdd(&fill[e], 1);
    const int gidx = offs[e] + p;
    token_list[gidx] = t;
    tok_w[gidx] = comb_w[t * 2 + j];
    slots[t * 2 + j] = gidx;
  }
}

// ---------------- combine + LayerNorm : moe = w0*ey0 + w1*ey1 + sh; fhb = LN(moe) ----------------
__global__ __launch_bounds__(256) void combine_ln_kernel(
    const unsigned short* __restrict__ eyb, const float* __restrict__ shb,
    const int* __restrict__ slots, const float* __restrict__ comb_w,
    const float* __restrict__ g, const float* __restrict__ b,
    float* __restrict__ moe, unsigned short* __restrict__ fhb) {
  const int wid = threadIdx.x >> 6, lane = threadIdx.x & 63;
  const int t = blockIdx.x * 4 + wid;
  const int s0 = slots[t * 2], s1 = slots[t * 2 + 1];
  const float w0 = comb_w[t * 2], w1 = comb_w[t * 2 + 1];
  const uint4 E0 = ((const uint4*)(eyb + (size_t)s0 * DIM))[lane];
  const uint4 E1 = ((const uint4*)(eyb + (size_t)s1 * DIM))[lane];
  const float4 sa = ((const float4*)(shb + (size_t)t * DIM))[lane * 2];
  const float4 sb = ((const float4*)(shb + (size_t)t * DIM))[lane * 2 + 1];
  const unsigned int e0[4] = {E0.x, E0.y, E0.z, E0.w};
  const unsigned int e1[4] = {E1.x, E1.y, E1.z, E1.w};
  const float shv[8] = {sa.x, sa.y, sa.z, sa.w, sb.x, sb.y, sb.z, sb.w};
  float m[8];
#pragma unroll
  for (int j = 0; j < 4; ++j) {
    m[2*j]   = w0 * b2f((unsigned short)(e0[j] & 0xffff)) + w1 * b2f((unsigned short)(e1[j] & 0xffff)) + shv[2*j];
    m[2*j+1] = w0 * b2f((unsigned short)(e0[j] >> 16))    + w1 * b2f((unsigned short)(e1[j] >> 16))    + shv[2*j+1];
  }
  float4* mo = (float4*)(moe + (size_t)t * DIM);
  mo[lane * 2]     = make_float4(m[0], m[1], m[2], m[3]);
  mo[lane * 2 + 1] = make_float4(m[4], m[5], m[6], m[7]);
  // LayerNorm over the 512 elements
  float s = 0.f;
#pragma unroll
  for (int j = 0; j < 8; ++j) s += m[j];
#pragma unroll
  for (int o = 32; o; o >>= 1) s += __shfl_xor(s, o, 64);
  const float mu = s * (1.f / DIM);
  float q = 0.f;
#pragma unroll
  for (int j = 0; j < 8; ++j) { const float d = m[j] - mu; q += d * d; }
#pragma unroll
  for (int o = 32; o; o >>= 1) q += __shfl_xor(q, o, 64);
  const float rs = rsqrtf(q * (1.f / DIM) + 1e-5f);
  const float4 ga = ((const float4*)g)[lane * 2], gb4 = ((const float4*)g)[lane * 2 + 1];
  const float4 ba = ((const float4*)b)[lane * 2], bb4 = ((const float4*)b)[lane * 2 + 1];
  const float gv[8] = {ga.x, ga.y, ga.z, ga.w, gb4.x, gb4.y, gb4.z, gb4.w};
  const float bv[8] = {ba.x, ba.y, ba.z, ba.w, bb4.x, bb4.y, bb4.z, bb4.w};
  ushort4 o0, o1;
  o0.x = f2b((m[0]-mu)*rs*gv[0]+bv[0]); o0.y = f2b((m[1]-mu)*rs*gv[1]+bv[1]);
  o0.z = f2b((m[2]-mu)*rs*gv[2]+bv[2]); o0.w = f2b((m[3]-mu)*rs*gv[3]+bv[3]);
  o1.x = f2b((m[4]-mu)*rs*gv[4]+bv[4]); o1.y = f2b((m[5]-mu)*rs*gv[5]+bv[5]);
  o1.z = f2b((m[6]-mu)*rs*gv[6]+bv[6]); o1.w = f2b((m[7]-mu)*rs*gv[7]+bv[7]);
  ((ushort4*)(fhb + (size_t)t * DIM))[lane * 2]     = o0;
  ((ushort4*)(fhb + (size_t)t * DIM))[lane * 2 + 1] = o1;
}

// ---------------- bf16 MFMA GEMM, 128x128x32 tile, async LDS staging, swizzled ----------------
// MODE 0: outA = silu(acc + bias) -> bf16
// MODE 1: outA = acc + bias -> bf16 (dense expert output rows)
// MODE 2: outp[row, n] = 0.25*(acc+bias)  (fp32, stride DIM)
// MODE 3: outp[row, n] = xres + mix + (acc+bias)
template <int MODE, bool EXPERT>
__global__ __launch_bounds__(256) void gemm_kernel(
    const unsigned short* __restrict__ A, int lda,
    const unsigned short* __restrict__ BT,  // bf16 [N, K] (per-expert stride N*K)
    const float* __restrict__ bias, int K, int N,
    const int* __restrict__ tiledesc, const int* __restrict__ token_list,
    unsigned short* __restrict__ outA, const float* __restrict__ mix,
    const float* __restrict__ xres, float* __restrict__ outp) {
  __shared__ unsigned short As[128 * 32];
  __shared__ unsigned short Bs[128 * 32];
  const int tid = threadIdx.x;
  int expert = 0, row0;
  if (EXPERT) {
    expert = tiledesc[blockIdx.y * 2];
    if (expert < 0) return;
    row0 = tiledesc[blockIdx.y * 2 + 1];
  } else {
    row0 = blockIdx.y * 128;
  }
  const int bn = blockIdx.x;
  const unsigned short* Bt = BT + (size_t)expert * N * K + (size_t)bn * 128 * K;
  const float* bp = bias + (EXPERT ? expert * N : 0) + bn * 128;

  // staging: thread tid stages row r_a (and r_a+64); LDS position p = tid&3;
  // swizzle: position p holds chunk c = (p - (row>>1)) & 3
  const int r_a = tid >> 2;
  const int c8 = ((((tid & 3) - (tid >> 3)) & 3)) << 3;
  const unsigned short* arow0; const unsigned short* arow1;
  if (EXPERT && MODE == 0) {
    // padded rows (token_list<0) load row 0: finite garbage, never read downstream
    int t0 = token_list[row0 + r_a];       if (t0 < 0) t0 = 0;
    int t1 = token_list[row0 + r_a + 64];  if (t1 < 0) t1 = 0;
    arow0 = A + (size_t)t0 * lda + c8;
    arow1 = A + (size_t)t1 * lda + c8;
  } else {
    arow0 = A + (size_t)(row0 + r_a) * lda + c8;
    arow1 = A + (size_t)(row0 + r_a + 64) * lda + c8;
  }
  const unsigned short* brow0 = Bt + (size_t)r_a * K + c8;
  const unsigned short* brow1 = Bt + (size_t)(r_a + 64) * K + c8;

  const int lane = tid & 63, wid = tid >> 6;
  const int wm = wid & 1, wn = wid >> 1;
  const int l15 = lane & 15, qd = lane >> 4;

  // wave-uniform LDS bases for async staging (dest = base + lane*16B)
  char* asb0 = (char*)As + wid * 1024;
  char* asb1 = (char*)As + 4096 + wid * 1024;
  char* bsb0 = (char*)Bs + wid * 1024;
  char* bsb1 = (char*)Bs + 4096 + wid * 1024;

  f32x4 acc[4][4] = {};
  const int rdsw = ((qd + (l15 >> 1)) & 3) * 8;  // swizzled chunk position for logical chunk qd
  const bf16x8* afp = (const bf16x8*)&As[(wm * 64 + l15) * 32 + rdsw];
  const bf16x8* bfp = (const bf16x8*)&Bs[(wn * 64 + l15) * 32 + rdsw];

  for (int k0 = 0; k0 < K; k0 += 32) {
    __syncthreads();  // previous iteration's LDS reads complete
    async16(asb0, arow0 + k0);
    async16(asb1, arow1 + k0);
    async16(bsb0, brow0 + k0);
    async16(bsb1, brow1 + k0);
    __syncthreads();  // barrier drains vmcnt -> staged data visible
    bf16x8 af[4], bq[4];
#pragma unroll
    for (int a = 0; a < 4; ++a) af[a] = afp[a * 64];
#pragma unroll
    for (int b2 = 0; b2 < 4; ++b2) bq[b2] = bfp[b2 * 64];
#pragma unroll
    for (int a = 0; a < 4; ++a)
#pragma unroll
      for (int b2 = 0; b2 < 4; ++b2)
        acc[a][b2] = __builtin_amdgcn_mfma_f32_16x16x32_bf16(af[a], bq[b2], acc[a][b2], 0, 0, 0);
  }

  // epilogue: D mapping col=lane&15, row=(lane>>4)*4+reg
  const int mloc = wm * 64 + qd * 4;
  const int nloc = wn * 64 + l15;
#pragma unroll
  for (int b2 = 0; b2 < 4; ++b2) {
    const int n = bn * 128 + nloc + b2 * 16;
    const float bv = bp[nloc + b2 * 16];
#pragma unroll
    for (int a = 0; a < 4; ++a) {
#pragma unroll
      for (int r = 0; r < 4; ++r) {
        const int m = mloc + a * 16 + r;
        const float val = acc[a][b2][r] + bv;
        if (MODE == 0) {
          const float sg = val / (1.f + __expf(-val));
          outA[(size_t)(row0 + m) * N + n] = f2b(sg);
        } else if (MODE == 1) {
          outA[(size_t)(row0 + m) * N + n] = f2b(val);
        } else if (MODE == 2) {
          outp[(size_t)(row0 + m) * DIM + n] = 0.25f * val;
        } else {
          const size_t o = (size_t)(row0 + m) * DIM + n;
          outp[o] = xres[o] + mix[o] + val;
        }
      }
    }
  }
}

extern "C" void kernel_launch(void* const* d_in, const int* in_sizes, int n_in,
                              void* d_out, int out_size, void* d_ws, size_t ws_size,
                              hipStream_t stream) {
  (void)in_sizes; (void)n_in; (void)out_size; (void)ws_size;
  const float* x    = (const float*)d_in[0];
  const float* lng  = (const float*)d_in[1];
  const float* lnb  = (const float*)d_in[2];
  const float* rw   = (const float*)d_in[3];
  const float* rb   = (const float*)d_in[4];
  const float* ew1  = (const float*)d_in[5];
  const float* eb1  = (const float*)d_in[6];
  const float* ew2  = (const float*)d_in[7];
  const float* eb2  = (const float*)d_in[8];
  const float* sw1  = (const float*)d_in[9];
  const float* sb1  = (const float*)d_in[10];
  const float* sw2  = (const float*)d_in[11];
  const float* sb2  = (const float*)d_in[12];
  const float* flng = (const float*)d_in[13];
  const float* flnb = (const float*)d_in[14];
  const float* fw1  = (const float*)d_in[15];
  const float* fb1  = (const float*)d_in[16];
  const float* fw2  = (const float*)d_in[17];
  const float* fb2  = (const float*)d_in[18];
  float* out = (float*)d_out;

  char* ws = (char*)d_ws;
  size_t off = 0;
  auto alloc = [&](size_t bytes) -> void* {
    void* p = ws + off;
    off += (bytes + 255) & ~(size_t)255;
    return p;
  };
  unsigned short* ew1T = (unsigned short*)alloc((size_t)NEXP * DIM * DHID * 2);
  unsigned short* ew2T = (unsigned short*)alloc((size_t)NEXP * DHID * DIM * 2);
  unsigned short* sw1T = (unsigned short*)alloc((size_t)DIM * DSH * 2);
  unsigned short* sw2T = (unsigned short*)alloc((size_t)DSH * DIM * 2);
  unsigned short* fw1T = (unsigned short*)alloc((size_t)DIM * DHID * 2);
  unsigned short* fw2T = (unsigned short*)alloc((size_t)DHID * DIM * 2);
  unsigned short* hb   = (unsigned short*)alloc((size_t)T_TOK * DIM * 2);
  unsigned short* fhb  = (unsigned short*)alloc((size_t)T_TOK * DIM * 2);
  unsigned short* Abuf = (unsigned short*)alloc((size_t)ROWSCAP * DHID * 2);
  unsigned short* eyb  = (unsigned short*)alloc((size_t)ROWSCAP * DIM * 2);
  float* shb = (float*)alloc((size_t)T_TOK * DIM * 4);
  float* moe = (float*)alloc((size_t)T_TOK * DIM * 4);
  int*   comb_idx = (int*)alloc((size_t)T_TOK * 2 * 4);
  float* comb_w   = (float*)alloc((size_t)T_TOK * 2 * 4);
  int*   slots    = (int*)alloc((size_t)T_TOK * 2 * 4);
  int* counts   = (int*)alloc(64);
  int* offs     = (int*)alloc(64);
  int* fill     = (int*)alloc(64);
  int* tiledesc = (int*)alloc(MAXTILES * 2 * 4);
  int*   token_list = (int*)alloc((size_t)ROWSCAP * 4);
  float* tok_w      = (float*)alloc((size_t)ROWSCAP * 4);

  hipMemsetAsync(counts, 0, 64, stream);
  hipMemsetAsync(token_list, 0xFF, (size_t)ROWSCAP * 4, stream);  // -1

  // all weight transposes in one dispatch (35840 tile-blocks)
  transpose_all<<<35840, 256, 0, stream>>>(ew1, ew2, sw1, sw2, fw1, fw2,
                                           ew1T, ew2T, sw1T, sw2T, fw1T, fw2T);

  ln_router_kernel<<<T_TOK / 4, 256, 0, stream>>>(x, lng, lnb, rw, rb, hb, comb_idx, comb_w, counts);
  plan_kernel<<<1, 64, 0, stream>>>(counts, offs, fill, tiledesc);
  scatter_kernel<<<T_TOK / 256, 256, 0, stream>>>(comb_idx, comb_w, offs, fill, token_list, tok_w, slots);

  // experts: silu(hg @ W1 + b1) -> Abuf ; (Abuf @ W2 + b2) -> eyb (dense, no atomics)
  gemm_kernel<0, true><<<dim3(DHID / 128, MAXTILES), 256, 0, stream>>>(
      hb, DIM, ew1T, eb1, DIM, DHID, tiledesc, token_list, Abuf, nullptr, nullptr, nullptr);
  gemm_kernel<1, true><<<dim3(DIM / 128, MAXTILES), 256, 0, stream>>>(
      Abuf, DHID, ew2T, eb2, DHID, DIM, tiledesc, token_list, eyb, nullptr, nullptr, nullptr);
  // shared expert -> shb (plain fp32 store, 0.25 folded in)
  gemm_kernel<0, false><<<dim3(DSH / 128, T_TOK / 128), 256, 0, stream>>>(
      hb, DIM, sw1T, sb1, DIM, DSH, nullptr, nullptr, Abuf, nullptr, nullptr, nullptr);
  gemm_kernel<2, false><<<dim3(DIM / 128, T_TOK / 128), 256, 0, stream>>>(
      Abuf, DSH, sw2T, sb2, DSH, DIM, nullptr, nullptr, nullptr, nullptr, nullptr, shb);
  // combine top-2 + shared, then LayerNorm -> fhb (bf16), moe (fp32)
  combine_ln_kernel<<<T_TOK / 4, 256, 0, stream>>>(eyb, shb, slots, comb_w, flng, flnb, moe, fhb);
  // final ff block
  gemm_kernel<0, false><<<dim3(DHID / 128, T_TOK / 128), 256, 0, stream>>>(
      fhb, DIM, fw1T, fb1, DIM, DHID, nullptr, nullptr, Abuf, nullptr, nullptr, nullptr);
  gemm_kernel<3, false><<<dim3(DIM / 128, T_TOK / 128), 256, 0, stream>>>(
      Abuf, DHID, fw2T, fb2, DHID, DIM, nullptr, nullptr, nullptr, moe, x, out);
}

// Round 4
// 436.605 us; speedup vs baseline: 1.3796x; 1.0976x over previous
//
#include <hip/hip_runtime.h>
#include <stdint.h>

// Problem constants
#define T_TOK 4096   // B*S
#define DIM   512    // D
#define NEXP  16     // E
#define DHID  2048   // 4*D
#define DSH   1024   // 2*D
#define ROWSCAP 10240  // 2*T + padding slack
#define MAXTILES 80    // sum ceil(c_e/128) <= 79

typedef __bf16 bf16x8 __attribute__((ext_vector_type(8)));
typedef float  f32x4  __attribute__((ext_vector_type(4)));
typedef unsigned short usv8 __attribute__((ext_vector_type(8)));

__device__ __forceinline__ unsigned short f2b(float f) {
  union { float f; unsigned int u; } un; un.f = f;
  unsigned int u = un.u + 0x7fffu + ((un.u >> 16) & 1u);  // RNE to bf16
  return (unsigned short)(u >> 16);
}
__device__ __forceinline__ float b2f(unsigned short u) {
  union { unsigned int u; float f; } un; un.u = ((unsigned int)u) << 16; return un.f;
}

__device__ __forceinline__ void async16(void* lds, const void* gp) {
  __builtin_amdgcn_global_load_lds(
      (const __attribute__((address_space(1))) unsigned int*)gp,
      (__attribute__((address_space(3))) unsigned int*)lds, 16, 0, 0);
}

// ---------------- 64x64 transpose tile: fp32 [R,C] -> bf16 [C,R] ----------------
// Load: float4/lane (coalesced). LDS: column-major bf16, stride 72 (16B-aligned rows).
// Store: ushort8/lane, 8 lanes sweep 128B of one dest row (coalesced).
__device__ __forceinline__ void transpose64(
    const float* __restrict__ s, unsigned short* __restrict__ d, int R, int C,
    int tx, int ty, unsigned short* tile) {
  const int tid = threadIdx.x;
  const int c0 = tx * 64, r0 = ty * 64;
  const int r = tid >> 4, j = tid & 15;
#pragma unroll
  for (int p = 0; p < 4; ++p) {
    const int row = r + p * 16;
    const float4 v = *(const float4*)&s[(size_t)(r0 + row) * C + c0 + j * 4];
    tile[(j * 4 + 0) * 72 + row] = f2b(v.x);
    tile[(j * 4 + 1) * 72 + row] = f2b(v.y);
    tile[(j * 4 + 2) * 72 + row] = f2b(v.z);
    tile[(j * 4 + 3) * 72 + row] = f2b(v.w);
  }
  __syncthreads();
  const int jj = tid & 7, cc = tid >> 3;
#pragma unroll
  for (int p = 0; p < 2; ++p) {
    const int c = cc + p * 32;
    const usv8 u = *(const usv8*)&tile[c * 72 + jj * 8];
    *(usv8*)&d[(size_t)(c0 + c) * R + r0 + jj * 8] = u;
  }
}

// ---------------- prep: all weight transposes + LN+router+top2, one dispatch ----------------
__global__ __launch_bounds__(256) void prep_kernel(
    const float* __restrict__ x, const float* __restrict__ g, const float* __restrict__ b,
    const float* __restrict__ rw, const float* __restrict__ rb,
    unsigned short* __restrict__ hbuf, int* __restrict__ comb_idx, float* __restrict__ comb_w,
    int* __restrict__ counts,
    const float* __restrict__ ew1, const float* __restrict__ ew2,
    const float* __restrict__ sw1, const float* __restrict__ sw2,
    const float* __restrict__ fw1, const float* __restrict__ fw2,
    unsigned short* __restrict__ ew1T, unsigned short* __restrict__ ew2T,
    unsigned short* __restrict__ sw1T, unsigned short* __restrict__ sw2T,
    unsigned short* __restrict__ fw1T, unsigned short* __restrict__ fw2T) {
  __shared__ unsigned short tile[64 * 72];
  __shared__ int hist[NEXP];
  const int id = blockIdx.x;
  if (id >= 1024) {
    // ---- transpose path ----
    int id2 = id - 1024;
    const float* s; unsigned short* d; int R, C, t, tx, ty;
    if (id2 < 4096)      { int bm = id2 >> 8; t = id2 & 255; R = 512;  C = 2048;
                           s = ew1 + (size_t)bm * R * C; d = ew1T + (size_t)bm * R * C;
                           tx = t & 31; ty = t >> 5; }
    else if (id2 < 8192) { id2 -= 4096; int bm = id2 >> 8; t = id2 & 255; R = 2048; C = 512;
                           s = ew2 + (size_t)bm * R * C; d = ew2T + (size_t)bm * R * C;
                           tx = t & 7;  ty = t >> 3; }
    else if (id2 < 8320) { t = id2 - 8192; R = 512;  C = 1024; s = sw1; d = sw1T; tx = t & 15; ty = t >> 4; }
    else if (id2 < 8448) { t = id2 - 8320; R = 1024; C = 512;  s = sw2; d = sw2T; tx = t & 7;  ty = t >> 3; }
    else if (id2 < 8704) { t = id2 - 8448; R = 512;  C = 2048; s = fw1; d = fw1T; tx = t & 31; ty = t >> 5; }
    else                 { t = id2 - 8704; R = 2048; C = 512;  s = fw2; d = fw2T; tx = t & 7;  ty = t >> 3; }
    transpose64(s, d, R, C, tx, ty, tile);
    return;
  }
  // ---- LN + router path (wave-per-token) ----
  const int wid = threadIdx.x >> 6, lane = threadIdx.x & 63;
  const int t = id * 4 + wid;
  if (threadIdx.x < NEXP) hist[threadIdx.x] = 0;
  __syncthreads();

  const float4* xr = (const float4*)(x + (size_t)t * DIM);
  const float4 va = xr[lane], vb = xr[lane + 64];
  float s = (va.x + va.y) + (va.z + va.w) + ((vb.x + vb.y) + (vb.z + vb.w));
#pragma unroll
  for (int o = 32; o; o >>= 1) s += __shfl_xor(s, o, 64);
  const float mu = s * (1.f / DIM);
  float da[4] = {va.x - mu, va.y - mu, va.z - mu, va.w - mu};
  float db[4] = {vb.x - mu, vb.y - mu, vb.z - mu, vb.w - mu};
  float q = (da[0]*da[0] + da[1]*da[1]) + (da[2]*da[2] + da[3]*da[3]) +
            ((db[0]*db[0] + db[1]*db[1]) + (db[2]*db[2] + db[3]*db[3]));
#pragma unroll
  for (int o = 32; o; o >>= 1) q += __shfl_xor(q, o, 64);
  const float rs = rsqrtf(q * (1.f / DIM) + 1e-5f);
  const float4 ga = ((const float4*)g)[lane], gb4 = ((const float4*)g)[lane + 64];
  const float4 ba = ((const float4*)b)[lane], bb4 = ((const float4*)b)[lane + 64];
  float ha[4], hbv[4];
  ha[0] = da[0] * rs * ga.x + ba.x;  ha[1] = da[1] * rs * ga.y + ba.y;
  ha[2] = da[2] * rs * ga.z + ba.z;  ha[3] = da[3] * rs * ga.w + ba.w;
  hbv[0] = db[0] * rs * gb4.x + bb4.x;  hbv[1] = db[1] * rs * gb4.y + bb4.y;
  hbv[2] = db[2] * rs * gb4.z + bb4.z;  hbv[3] = db[3] * rs * gb4.w + bb4.w;
  ushort4 ua = {f2b(ha[0]), f2b(ha[1]), f2b(ha[2]), f2b(ha[3])};
  ushort4 ub = {f2b(hbv[0]), f2b(hbv[1]), f2b(hbv[2]), f2b(hbv[3])};
  ((ushort4*)(hbuf + (size_t)t * DIM))[lane] = ua;
  ((ushort4*)(hbuf + (size_t)t * DIM))[lane + 64] = ub;

  float p[NEXP];
#pragma unroll
  for (int e = 0; e < NEXP; ++e) p[e] = 0.f;
  const int col0 = lane * 4;
#pragma unroll
  for (int half = 0; half < 2; ++half) {
#pragma unroll
    for (int j = 0; j < 4; ++j) {
      const int col = half * 256 + col0 + j;
      const float hv = half ? hbv[j] : ha[j];
      const float4* wr = (const float4*)(rw + (size_t)col * NEXP);
#pragma unroll
      for (int qq = 0; qq < 4; ++qq) {
        const float4 w = wr[qq];
        p[qq * 4 + 0] += hv * w.x;  p[qq * 4 + 1] += hv * w.y;
        p[qq * 4 + 2] += hv * w.z;  p[qq * 4 + 3] += hv * w.w;
      }
    }
  }
#pragma unroll
  for (int o = 32; o; o >>= 1) {
#pragma unroll
    for (int e = 0; e < NEXP; ++e) p[e] += __shfl_xor(p[e], o, 64);
  }
  float mx = -1e30f;
#pragma unroll
  for (int e = 0; e < NEXP; ++e) {
    p[e] = (p[e] + rb[e]) * (1.f / 0.7f);
    mx = fmaxf(mx, p[e]);
  }
  float ge[NEXP], se = 0.f;
#pragma unroll
  for (int e = 0; e < NEXP; ++e) { ge[e] = __expf(p[e] - mx); se += ge[e]; }
  const float inv = 1.f / se;
  int i0 = 0; float m0 = ge[0];
#pragma unroll
  for (int e = 1; e < NEXP; ++e) if (ge[e] > m0) { m0 = ge[e]; i0 = e; }
  int i1 = -1; float m1 = -1.f;
#pragma unroll
  for (int e = 0; e < NEXP; ++e) if (e != i0 && ge[e] > m1) { m1 = ge[e]; i1 = e; }
  if (lane == 0) {
    comb_idx[t * 2] = i0; comb_idx[t * 2 + 1] = i1;
    comb_w[t * 2] = m0 * inv; comb_w[t * 2 + 1] = m1 * inv;
    atomicAdd(&hist[i0], 1); atomicAdd(&hist[i1], 1);
  }
  __syncthreads();
  if (threadIdx.x < NEXP) {
    const int c = hist[threadIdx.x];
    if (c) atomicAdd(&counts[threadIdx.x], c);
  }
}

// ---------------- plan: padded segment offsets + tile descriptors ----------------
__global__ void plan_kernel(const int* __restrict__ counts, int* __restrict__ offs,
                            int* __restrict__ fill, int* __restrict__ tiledesc) {
  if (threadIdx.x == 0) {
    int run = 0, tix = 0;
    for (int e = 0; e < NEXP; ++e) {
      offs[e] = run;
      const int nt = (counts[e] + 127) >> 7;
      for (int i = 0; i < nt; ++i) { tiledesc[tix * 2] = e; tiledesc[tix * 2 + 1] = run + i * 128; ++tix; }
      run += nt * 128;
    }
    for (; tix < MAXTILES; ++tix) { tiledesc[tix * 2] = -1; tiledesc[tix * 2 + 1] = 0; }
  }
  if (threadIdx.x < NEXP) fill[threadIdx.x] = 0;
}

// ---------------- scatter tokens into expert segments (records slots) ----------------
__global__ __launch_bounds__(256) void scatter_kernel(
    const int* __restrict__ comb_idx, const float* __restrict__ comb_w,
    const int* __restrict__ offs, int* __restrict__ fill,
    int* __restrict__ token_list, int* __restrict__ slots) {
  const int t = blockIdx.x * 256 + threadIdx.x;
#pragma unroll
  for (int j = 0; j < 2; ++j) {
    const int e = comb_idx[t * 2 + j];
    const int p = atomicAdd(&fill[e], 1);
    const int gidx = offs[e] + p;
    token_list[gidx] = t;
    slots[t * 2 + j] = gidx;
  }
}

// ---------------- combine + LayerNorm ----------------
__global__ __launch_bounds__(256) void combine_ln_kernel(
    const unsigned short* __restrict__ eyb, const float* __restrict__ shb,
    const int* __restrict__ slots, const float* __restrict__ comb_w,
    const float* __restrict__ g, const float* __restrict__ b,
    float* __restrict__ moe, unsigned short* __restrict__ fhb) {
  const int wid = threadIdx.x >> 6, lane = threadIdx.x & 63;
  const int t = blockIdx.x * 4 + wid;
  const int s0 = slots[t * 2], s1 = slots[t * 2 + 1];
  const float w0 = comb_w[t * 2], w1 = comb_w[t * 2 + 1];
  const uint4 E0 = ((const uint4*)(eyb + (size_t)s0 * DIM))[lane];
  const uint4 E1 = ((const uint4*)(eyb + (size_t)s1 * DIM))[lane];
  const float4 sa = ((const float4*)(shb + (size_t)t * DIM))[lane * 2];
  const float4 sb = ((const float4*)(shb + (size_t)t * DIM))[lane * 2 + 1];
  const unsigned int e0[4] = {E0.x, E0.y, E0.z, E0.w};
  const unsigned int e1[4] = {E1.x, E1.y, E1.z, E1.w};
  const float shv[8] = {sa.x, sa.y, sa.z, sa.w, sb.x, sb.y, sb.z, sb.w};
  float m[8];
#pragma unroll
  for (int j = 0; j < 4; ++j) {
    m[2*j]   = w0 * b2f((unsigned short)(e0[j] & 0xffff)) + w1 * b2f((unsigned short)(e1[j] & 0xffff)) + shv[2*j];
    m[2*j+1] = w0 * b2f((unsigned short)(e0[j] >> 16))    + w1 * b2f((unsigned short)(e1[j] >> 16))    + shv[2*j+1];
  }
  float4* mo = (float4*)(moe + (size_t)t * DIM);
  mo[lane * 2]     = make_float4(m[0], m[1], m[2], m[3]);
  mo[lane * 2 + 1] = make_float4(m[4], m[5], m[6], m[7]);
  float s = 0.f;
#pragma unroll
  for (int j = 0; j < 8; ++j) s += m[j];
#pragma unroll
  for (int o = 32; o; o >>= 1) s += __shfl_xor(s, o, 64);
  const float mu = s * (1.f / DIM);
  float q = 0.f;
#pragma unroll
  for (int j = 0; j < 8; ++j) { const float d = m[j] - mu; q += d * d; }
#pragma unroll
  for (int o = 32; o; o >>= 1) q += __shfl_xor(q, o, 64);
  const float rs = rsqrtf(q * (1.f / DIM) + 1e-5f);
  const float4 ga = ((const float4*)g)[lane * 2], gb4 = ((const float4*)g)[lane * 2 + 1];
  const float4 ba = ((const float4*)b)[lane * 2], bb4 = ((const float4*)b)[lane * 2 + 1];
  const float gv[8] = {ga.x, ga.y, ga.z, ga.w, gb4.x, gb4.y, gb4.z, gb4.w};
  const float bv[8] = {ba.x, ba.y, ba.z, ba.w, bb4.x, bb4.y, bb4.z, bb4.w};
  ushort4 o0, o1;
  o0.x = f2b((m[0]-mu)*rs*gv[0]+bv[0]); o0.y = f2b((m[1]-mu)*rs*gv[1]+bv[1]);
  o0.z = f2b((m[2]-mu)*rs*gv[2]+bv[2]); o0.w = f2b((m[3]-mu)*rs*gv[3]+bv[3]);
  o1.x = f2b((m[4]-mu)*rs*gv[4]+bv[4]); o1.y = f2b((m[5]-mu)*rs*gv[5]+bv[5]);
  o1.z = f2b((m[6]-mu)*rs*gv[6]+bv[6]); o1.w = f2b((m[7]-mu)*rs*gv[7]+bv[7]);
  ((ushort4*)(fhb + (size_t)t * DIM))[lane * 2]     = o0;
  ((ushort4*)(fhb + (size_t)t * DIM))[lane * 2 + 1] = o1;
}

// ---------------- bf16 MFMA GEMM body, 128x128x32 tile, async staging, swizzled ----------------
// MODE 0: outA = silu(acc+bias) bf16 | MODE 1: outA = acc+bias bf16
// MODE 2: outp = 0.25*(acc+bias) fp32 | MODE 3: outp = xres + mix + (acc+bias)
template <int MODE, bool EXPERT>
__device__ __forceinline__ void gemm_body(
    const unsigned short* __restrict__ A, int lda,
    const unsigned short* __restrict__ BT, const float* __restrict__ bias,
    int K, int N, int row0, int expert, int bn,
    const int* __restrict__ token_list,
    unsigned short* __restrict__ outA, const float* __restrict__ mix,
    const float* __restrict__ xres, float* __restrict__ outp,
    unsigned short* As, unsigned short* Bs) {
  const int tid = threadIdx.x;
  const unsigned short* Bt = BT + (size_t)expert * N * K + (size_t)bn * 128 * K;
  const float* bp = bias + (EXPERT ? expert * N : 0) + bn * 128;

  const int r_a = tid >> 2;
  const int c8 = ((((tid & 3) - (tid >> 3)) & 3)) << 3;
  const unsigned short* arow0; const unsigned short* arow1;
  if (EXPERT && MODE == 0) {
    int t0 = token_list[row0 + r_a];       if (t0 < 0) t0 = 0;
    int t1 = token_list[row0 + r_a + 64];  if (t1 < 0) t1 = 0;
    arow0 = A + (size_t)t0 * lda + c8;
    arow1 = A + (size_t)t1 * lda + c8;
  } else {
    arow0 = A + (size_t)(row0 + r_a) * lda + c8;
    arow1 = A + (size_t)(row0 + r_a + 64) * lda + c8;
  }
  const unsigned short* brow0 = Bt + (size_t)r_a * K + c8;
  const unsigned short* brow1 = Bt + (size_t)(r_a + 64) * K + c8;

  const int lane = tid & 63, wid = tid >> 6;
  const int wm = wid & 1, wn = wid >> 1;
  const int l15 = lane & 15, qd = lane >> 4;

  char* asb0 = (char*)As + wid * 1024;
  char* asb1 = (char*)As + 4096 + wid * 1024;
  char* bsb0 = (char*)Bs + wid * 1024;
  char* bsb1 = (char*)Bs + 4096 + wid * 1024;

  f32x4 acc[4][4] = {};
  const int rdsw = ((qd + (l15 >> 1)) & 3) * 8;
  const bf16x8* afp = (const bf16x8*)&As[(wm * 64 + l15) * 32 + rdsw];
  const bf16x8* bfp = (const bf16x8*)&Bs[(wn * 64 + l15) * 32 + rdsw];

  for (int k0 = 0; k0 < K; k0 += 32) {
    __syncthreads();
    async16(asb0, arow0 + k0);
    async16(asb1, arow1 + k0);
    async16(bsb0, brow0 + k0);
    async16(bsb1, brow1 + k0);
    __syncthreads();
    bf16x8 af[4], bq[4];
#pragma unroll
    for (int a = 0; a < 4; ++a) af[a] = afp[a * 64];
#pragma unroll
    for (int b2 = 0; b2 < 4; ++b2) bq[b2] = bfp[b2 * 64];
#pragma unroll
    for (int a = 0; a < 4; ++a)
#pragma unroll
      for (int b2 = 0; b2 < 4; ++b2)
        acc[a][b2] = __builtin_amdgcn_mfma_f32_16x16x32_bf16(af[a], bq[b2], acc[a][b2], 0, 0, 0);
  }

  const int mloc = wm * 64 + qd * 4;
  const int nloc = wn * 64 + l15;
#pragma unroll
  for (int b2 = 0; b2 < 4; ++b2) {
    const int n = bn * 128 + nloc + b2 * 16;
    const float bv = bp[nloc + b2 * 16];
#pragma unroll
    for (int a = 0; a < 4; ++a) {
#pragma unroll
      for (int r = 0; r < 4; ++r) {
        const int m = mloc + a * 16 + r;
        const float val = acc[a][b2][r] + bv;
        if (MODE == 0) {
          const float sg = val / (1.f + __expf(-val));
          outA[(size_t)(row0 + m) * N + n] = f2b(sg);
        } else if (MODE == 1) {
          outA[(size_t)(row0 + m) * N + n] = f2b(val);
        } else if (MODE == 2) {
          outp[(size_t)(row0 + m) * DIM + n] = 0.25f * val;
        } else {
          const size_t o = (size_t)(row0 + m) * DIM + n;
          outp[o] = xres[o] + mix[o] + val;
        }
      }
    }
  }
}

// ---- fused pair 1: expert GEMM1 (1280 blocks) + shared GEMM1 (256 blocks) ----
__global__ __launch_bounds__(256) void gemm_g1(
    const unsigned short* __restrict__ hb,
    const unsigned short* __restrict__ ew1T, const float* __restrict__ eb1,
    const unsigned short* __restrict__ sw1T, const float* __restrict__ sb1,
    const int* __restrict__ tiledesc, const int* __restrict__ token_list,
    unsigned short* __restrict__ Abuf, unsigned short* __restrict__ Sbuf) {
  __shared__ unsigned short As[128 * 32];
  __shared__ unsigned short Bs[128 * 32];
  const int id = blockIdx.x;
  if (id < MAXTILES * 16) {
    const int by = id >> 4, bn = id & 15;
    const int expert = tiledesc[by * 2];
    if (expert < 0) return;
    const int row0 = tiledesc[by * 2 + 1];
    gemm_body<0, true>(hb, DIM, ew1T, eb1, DIM, DHID, row0, expert, bn,
                       token_list, Abuf, nullptr, nullptr, nullptr, As, Bs);
  } else {
    const int id2 = id - MAXTILES * 16;
    const int by = id2 >> 3, bn = id2 & 7;
    gemm_body<0, false>(hb, DIM, sw1T, sb1, DIM, DSH, by * 128, 0, bn,
                        nullptr, Sbuf, nullptr, nullptr, nullptr, As, Bs);
  }
}

// ---- fused pair 2: expert GEMM2 (320 blocks) + shared GEMM2 (128 blocks) ----
__global__ __launch_bounds__(256) void gemm_g2(
    const unsigned short* __restrict__ Abuf,
    const unsigned short* __restrict__ ew2T, const float* __restrict__ eb2,
    const unsigned short* __restrict__ Sbuf,
    const unsigned short* __restrict__ sw2T, const float* __restrict__ sb2,
    const int* __restrict__ tiledesc,
    unsigned short* __restrict__ eyb, float* __restrict__ shb) {
  __shared__ unsigned short As[128 * 32];
  __shared__ unsigned short Bs[128 * 32];
  const int id = blockIdx.x;
  if (id < MAXTILES * 4) {
    const int by = id >> 2, bn = id & 3;
    const int expert = tiledesc[by * 2];
    if (expert < 0) return;
    const int row0 = tiledesc[by * 2 + 1];
    gemm_body<1, true>(Abuf, DHID, ew2T, eb2, DHID, DIM, row0, expert, bn,
                       nullptr, eyb, nullptr, nullptr, nullptr, As, Bs);
  } else {
    const int id2 = id - MAXTILES * 4;
    const int by = id2 >> 2, bn = id2 & 3;
    gemm_body<2, false>(Sbuf, DSH, sw2T, sb2, DSH, DIM, by * 128, 0, bn,
                        nullptr, nullptr, nullptr, nullptr, shb, As, Bs);
  }
}

// ---- standalone GEMM for the final ff block ----
template <int MODE>
__global__ __launch_bounds__(256) void gemm_kernel(
    const unsigned short* __restrict__ A, int lda,
    const unsigned short* __restrict__ BT, const float* __restrict__ bias, int K, int N,
    unsigned short* __restrict__ outA, const float* __restrict__ mix,
    const float* __restrict__ xres, float* __restrict__ outp) {
  __shared__ unsigned short As[128 * 32];
  __shared__ unsigned short Bs[128 * 32];
  gemm_body<MODE, false>(A, lda, BT, bias, K, N, blockIdx.y * 128, 0, blockIdx.x,
                         nullptr, outA, mix, xres, outp, As, Bs);
}

extern "C" void kernel_launch(void* const* d_in, const int* in_sizes, int n_in,
                              void* d_out, int out_size, void* d_ws, size_t ws_size,
                              hipStream_t stream) {
  (void)in_sizes; (void)n_in; (void)out_size; (void)ws_size;
  const float* x    = (const float*)d_in[0];
  const float* lng  = (const float*)d_in[1];
  const float* lnb  = (const float*)d_in[2];
  const float* rw   = (const float*)d_in[3];
  const float* rb   = (const float*)d_in[4];
  const float* ew1  = (const float*)d_in[5];
  const float* eb1  = (const float*)d_in[6];
  const float* ew2  = (const float*)d_in[7];
  const float* eb2  = (const float*)d_in[8];
  const float* sw1  = (const float*)d_in[9];
  const float* sb1  = (const float*)d_in[10];
  const float* sw2  = (const float*)d_in[11];
  const float* sb2  = (const float*)d_in[12];
  const float* flng = (const float*)d_in[13];
  const float* flnb = (const float*)d_in[14];
  const float* fw1  = (const float*)d_in[15];
  const float* fb1  = (const float*)d_in[16];
  const float* fw2  = (const float*)d_in[17];
  const float* fb2  = (const float*)d_in[18];
  float* out = (float*)d_out;

  char* ws = (char*)d_ws;
  size_t off = 0;
  auto alloc = [&](size_t bytes) -> void* {
    void* p = ws + off;
    off += (bytes + 255) & ~(size_t)255;
    return p;
  };
  unsigned short* ew1T = (unsigned short*)alloc((size_t)NEXP * DIM * DHID * 2);
  unsigned short* ew2T = (unsigned short*)alloc((size_t)NEXP * DHID * DIM * 2);
  unsigned short* sw1T = (unsigned short*)alloc((size_t)DIM * DSH * 2);
  unsigned short* sw2T = (unsigned short*)alloc((size_t)DSH * DIM * 2);
  unsigned short* fw1T = (unsigned short*)alloc((size_t)DIM * DHID * 2);
  unsigned short* fw2T = (unsigned short*)alloc((size_t)DHID * DIM * 2);
  unsigned short* hb   = (unsigned short*)alloc((size_t)T_TOK * DIM * 2);
  unsigned short* fhb  = (unsigned short*)alloc((size_t)T_TOK * DIM * 2);
  unsigned short* Abuf = (unsigned short*)alloc((size_t)ROWSCAP * DHID * 2);
  unsigned short* Sbuf = (unsigned short*)alloc((size_t)T_TOK * DSH * 2);
  unsigned short* eyb  = (unsigned short*)alloc((size_t)ROWSCAP * DIM * 2);
  float* shb = (float*)alloc((size_t)T_TOK * DIM * 4);
  float* moe = (float*)alloc((size_t)T_TOK * DIM * 4);
  int*   comb_idx = (int*)alloc((size_t)T_TOK * 2 * 4);
  float* comb_w   = (float*)alloc((size_t)T_TOK * 2 * 4);
  int*   slots    = (int*)alloc((size_t)T_TOK * 2 * 4);
  int* counts   = (int*)alloc(64);
  int* offs     = (int*)alloc(64);
  int* fill     = (int*)alloc(64);
  int* tiledesc = (int*)alloc(MAXTILES * 2 * 4);
  int* token_list = (int*)alloc((size_t)ROWSCAP * 4);

  hipMemsetAsync(counts, 0, 64, stream);
  hipMemsetAsync(token_list, 0xFF, (size_t)ROWSCAP * 4, stream);  // -1

  // transposes (8960 blocks) + LN/router (1024 blocks) in one dispatch
  prep_kernel<<<9984, 256, 0, stream>>>(x, lng, lnb, rw, rb, hb, comb_idx, comb_w, counts,
                                        ew1, ew2, sw1, sw2, fw1, fw2,
                                        ew1T, ew2T, sw1T, sw2T, fw1T, fw2T);
  plan_kernel<<<1, 64, 0, stream>>>(counts, offs, fill, tiledesc);
  scatter_kernel<<<T_TOK / 256, 256, 0, stream>>>(comb_idx, comb_w, offs, fill, token_list, slots);

  // expert G1 + shared G1 (independent, fused into one dispatch)
  gemm_g1<<<MAXTILES * 16 + 256, 256, 0, stream>>>(hb, ew1T, eb1, sw1T, sb1,
                                                   tiledesc, token_list, Abuf, Sbuf);
  // expert G2 + shared G2 (both depend only on the pair-1 dispatch)
  gemm_g2<<<MAXTILES * 4 + 128, 256, 0, stream>>>(Abuf, ew2T, eb2, Sbuf, sw2T, sb2,
                                                  tiledesc, eyb, shb);
  combine_ln_kernel<<<T_TOK / 4, 256, 0, stream>>>(eyb, shb, slots, comb_w, flng, flnb, moe, fhb);
  gemm_kernel<0><<<dim3(DHID / 128, T_TOK / 128), 256, 0, stream>>>(
      fhb, DIM, fw1T, fb1, DIM, DHID, Abuf, nullptr, nullptr, nullptr);
  gemm_kernel<3><<<dim3(DIM / 128, T_TOK / 128), 256, 0, stream>>>(
      Abuf, DHID, fw2T, fb2, DHID, DIM, nullptr, moe, x, out);
}

// Round 5
// 400.734 us; speedup vs baseline: 1.5031x; 1.0895x over previous
//
#include <hip/hip_runtime.h>
#include <stdint.h>

// Problem constants
#define T_TOK 4096   // B*S
#define DIM   512    // D
#define NEXP  16     // E
#define DHID  2048   // 4*D
#define DSH   1024   // 2*D
#define ROWSCAP 10240  // 2*T + padding slack
#define MAXTILES 80    // sum ceil(c_e/128) <= 79

typedef __bf16 bf16x8 __attribute__((ext_vector_type(8)));
typedef float  f32x4  __attribute__((ext_vector_type(4)));
typedef unsigned short usv8 __attribute__((ext_vector_type(8)));

__device__ __forceinline__ unsigned short f2b(float f) {
  union { float f; unsigned int u; } un; un.f = f;
  unsigned int u = un.u + 0x7fffu + ((un.u >> 16) & 1u);  // RNE to bf16
  return (unsigned short)(u >> 16);
}
__device__ __forceinline__ float b2f(unsigned short u) {
  union { unsigned int u; float f; } un; un.u = ((unsigned int)u) << 16; return un.f;
}

__device__ __forceinline__ void async16(void* lds, const void* gp) {
  __builtin_amdgcn_global_load_lds(
      (const __attribute__((address_space(1))) unsigned int*)gp,
      (__attribute__((address_space(3))) unsigned int*)lds, 16, 0, 0);
}

// ---------------- 64x64 transpose tile: fp32 [R,C] -> bf16 [C,R] ----------------
// LDS: float row-major [64][65] (65 = 1 mod 32 -> all scalar accesses 2-way = free).
// Load: float4/lane coalesced; Store: ushort8 (16B)/lane coalesced.
__device__ __forceinline__ void transpose64(
    const float* __restrict__ s, unsigned short* __restrict__ d, int R, int C,
    int tx, int ty, float* tile) {
  const int tid = threadIdx.x;
  const int c0 = tx * 64, r0 = ty * 64;
  const int r = tid >> 4, j4 = (tid & 15) * 4;
#pragma unroll
  for (int p = 0; p < 4; ++p) {
    const int row = r + p * 16;
    const float4 v = *(const float4*)&s[(size_t)(r0 + row) * C + c0 + j4];
    tile[row * 65 + j4 + 0] = v.x;
    tile[row * 65 + j4 + 1] = v.y;
    tile[row * 65 + j4 + 2] = v.z;
    tile[row * 65 + j4 + 3] = v.w;
  }
  __syncthreads();
  const int jj = tid & 7, cc = tid >> 3;
#pragma unroll
  for (int p = 0; p < 2; ++p) {
    const int c = cc + p * 32;
    usv8 u;
#pragma unroll
    for (int i = 0; i < 8; ++i) u[i] = f2b(tile[(jj * 8 + i) * 65 + c]);
    *(usv8*)&d[(size_t)(c0 + c) * R + r0 + jj * 8] = u;
  }
}

// ---------------- prep: all weight transposes + LN+router+top2, one dispatch ----------------
__global__ __launch_bounds__(256) void prep_kernel(
    const float* __restrict__ x, const float* __restrict__ g, const float* __restrict__ b,
    const float* __restrict__ rw, const float* __restrict__ rb,
    unsigned short* __restrict__ hbuf, int* __restrict__ comb_idx, float* __restrict__ comb_w,
    int* __restrict__ counts,
    const float* __restrict__ ew1, const float* __restrict__ ew2,
    const float* __restrict__ sw1, const float* __restrict__ sw2,
    const float* __restrict__ fw1, const float* __restrict__ fw2,
    unsigned short* __restrict__ ew1T, unsigned short* __restrict__ ew2T,
    unsigned short* __restrict__ sw1T, unsigned short* __restrict__ sw2T,
    unsigned short* __restrict__ fw1T, unsigned short* __restrict__ fw2T) {
  __shared__ float tile[64 * 65];
  __shared__ int hist[NEXP];
  const int id = blockIdx.x;
  if (id >= 1024) {
    // ---- transpose path ----
    int id2 = id - 1024;
    const float* s; unsigned short* d; int R, C, t, tx, ty;
    if (id2 < 4096)      { int bm = id2 >> 8; t = id2 & 255; R = 512;  C = 2048;
                           s = ew1 + (size_t)bm * R * C; d = ew1T + (size_t)bm * R * C;
                           tx = t & 31; ty = t >> 5; }
    else if (id2 < 8192) { id2 -= 4096; int bm = id2 >> 8; t = id2 & 255; R = 2048; C = 512;
                           s = ew2 + (size_t)bm * R * C; d = ew2T + (size_t)bm * R * C;
                           tx = t & 7;  ty = t >> 3; }
    else if (id2 < 8320) { t = id2 - 8192; R = 512;  C = 1024; s = sw1; d = sw1T; tx = t & 15; ty = t >> 4; }
    else if (id2 < 8448) { t = id2 - 8320; R = 1024; C = 512;  s = sw2; d = sw2T; tx = t & 7;  ty = t >> 3; }
    else if (id2 < 8704) { t = id2 - 8448; R = 512;  C = 2048; s = fw1; d = fw1T; tx = t & 31; ty = t >> 5; }
    else                 { t = id2 - 8704; R = 2048; C = 512;  s = fw2; d = fw2T; tx = t & 7;  ty = t >> 3; }
    transpose64(s, d, R, C, tx, ty, tile);
    return;
  }
  // ---- LN + router path (wave-per-token) ----
  const int wid = threadIdx.x >> 6, lane = threadIdx.x & 63;
  const int t = id * 4 + wid;
  if (threadIdx.x < NEXP) hist[threadIdx.x] = 0;
  __syncthreads();

  const float4* xr = (const float4*)(x + (size_t)t * DIM);
  const float4 va = xr[lane], vb = xr[lane + 64];
  float s = (va.x + va.y) + (va.z + va.w) + ((vb.x + vb.y) + (vb.z + vb.w));
#pragma unroll
  for (int o = 32; o; o >>= 1) s += __shfl_xor(s, o, 64);
  const float mu = s * (1.f / DIM);
  float da[4] = {va.x - mu, va.y - mu, va.z - mu, va.w - mu};
  float db[4] = {vb.x - mu, vb.y - mu, vb.z - mu, vb.w - mu};
  float q = (da[0]*da[0] + da[1]*da[1]) + (da[2]*da[2] + da[3]*da[3]) +
            ((db[0]*db[0] + db[1]*db[1]) + (db[2]*db[2] + db[3]*db[3]));
#pragma unroll
  for (int o = 32; o; o >>= 1) q += __shfl_xor(q, o, 64);
  const float rs = rsqrtf(q * (1.f / DIM) + 1e-5f);
  const float4 ga = ((const float4*)g)[lane], gb4 = ((const float4*)g)[lane + 64];
  const float4 ba = ((const float4*)b)[lane], bb4 = ((const float4*)b)[lane + 64];
  float ha[4], hbv[4];
  ha[0] = da[0] * rs * ga.x + ba.x;  ha[1] = da[1] * rs * ga.y + ba.y;
  ha[2] = da[2] * rs * ga.z + ba.z;  ha[3] = da[3] * rs * ga.w + ba.w;
  hbv[0] = db[0] * rs * gb4.x + bb4.x;  hbv[1] = db[1] * rs * gb4.y + bb4.y;
  hbv[2] = db[2] * rs * gb4.z + bb4.z;  hbv[3] = db[3] * rs * gb4.w + bb4.w;
  ushort4 ua = {f2b(ha[0]), f2b(ha[1]), f2b(ha[2]), f2b(ha[3])};
  ushort4 ub = {f2b(hbv[0]), f2b(hbv[1]), f2b(hbv[2]), f2b(hbv[3])};
  ((ushort4*)(hbuf + (size_t)t * DIM))[lane] = ua;
  ((ushort4*)(hbuf + (size_t)t * DIM))[lane + 64] = ub;

  float p[NEXP];
#pragma unroll
  for (int e = 0; e < NEXP; ++e) p[e] = 0.f;
  const int col0 = lane * 4;
#pragma unroll
  for (int half = 0; half < 2; ++half) {
#pragma unroll
    for (int j = 0; j < 4; ++j) {
      const int col = half * 256 + col0 + j;
      const float hv = half ? hbv[j] : ha[j];
      const float4* wr = (const float4*)(rw + (size_t)col * NEXP);
#pragma unroll
      for (int qq = 0; qq < 4; ++qq) {
        const float4 w = wr[qq];
        p[qq * 4 + 0] += hv * w.x;  p[qq * 4 + 1] += hv * w.y;
        p[qq * 4 + 2] += hv * w.z;  p[qq * 4 + 3] += hv * w.w;
      }
    }
  }
#pragma unroll
  for (int o = 32; o; o >>= 1) {
#pragma unroll
    for (int e = 0; e < NEXP; ++e) p[e] += __shfl_xor(p[e], o, 64);
  }
  float mx = -1e30f;
#pragma unroll
  for (int e = 0; e < NEXP; ++e) {
    p[e] = (p[e] + rb[e]) * (1.f / 0.7f);
    mx = fmaxf(mx, p[e]);
  }
  float ge[NEXP], se = 0.f;
#pragma unroll
  for (int e = 0; e < NEXP; ++e) { ge[e] = __expf(p[e] - mx); se += ge[e]; }
  const float inv = 1.f / se;
  int i0 = 0; float m0 = ge[0];
#pragma unroll
  for (int e = 1; e < NEXP; ++e) if (ge[e] > m0) { m0 = ge[e]; i0 = e; }
  int i1 = -1; float m1 = -1.f;
#pragma unroll
  for (int e = 0; e < NEXP; ++e) if (e != i0 && ge[e] > m1) { m1 = ge[e]; i1 = e; }
  if (lane == 0) {
    comb_idx[t * 2] = i0; comb_idx[t * 2 + 1] = i1;
    comb_w[t * 2] = m0 * inv; comb_w[t * 2 + 1] = m1 * inv;
    atomicAdd(&hist[i0], 1); atomicAdd(&hist[i1], 1);
  }
  __syncthreads();
  if (threadIdx.x < NEXP) {
    const int c = hist[threadIdx.x];
    if (c) atomicAdd(&counts[threadIdx.x], c);
  }
}

// ---------------- plan: padded segment offsets + tile descriptors ----------------
__global__ void plan_kernel(const int* __restrict__ counts, int* __restrict__ offs,
                            int* __restrict__ fill, int* __restrict__ tiledesc) {
  if (threadIdx.x == 0) {
    int run = 0, tix = 0;
    for (int e = 0; e < NEXP; ++e) {
      offs[e] = run;
      const int nt = (counts[e] + 127) >> 7;
      for (int i = 0; i < nt; ++i) { tiledesc[tix * 2] = e; tiledesc[tix * 2 + 1] = run + i * 128; ++tix; }
      run += nt * 128;
    }
    for (; tix < MAXTILES; ++tix) { tiledesc[tix * 2] = -1; tiledesc[tix * 2 + 1] = 0; }
  }
  if (threadIdx.x < NEXP) fill[threadIdx.x] = 0;
}

// ---------------- scatter tokens into expert segments (records slots) ----------------
__global__ __launch_bounds__(256) void scatter_kernel(
    const int* __restrict__ comb_idx, const float* __restrict__ comb_w,
    const int* __restrict__ offs, int* __restrict__ fill,
    int* __restrict__ token_list, int* __restrict__ slots) {
  const int t = blockIdx.x * 256 + threadIdx.x;
#pragma unroll
  for (int j = 0; j < 2; ++j) {
    const int e = comb_idx[t * 2 + j];
    const int p = atomicAdd(&fill[e], 1);
    const int gidx = offs[e] + p;
    token_list[gidx] = t;
    slots[t * 2 + j] = gidx;
  }
}

// ---------------- combine + LayerNorm ----------------
__global__ __launch_bounds__(256) void combine_ln_kernel(
    const unsigned short* __restrict__ eyb, const float* __restrict__ shb,
    const int* __restrict__ slots, const float* __restrict__ comb_w,
    const float* __restrict__ g, const float* __restrict__ b,
    float* __restrict__ moe, unsigned short* __restrict__ fhb) {
  const int wid = threadIdx.x >> 6, lane = threadIdx.x & 63;
  const int t = blockIdx.x * 4 + wid;
  const int s0 = slots[t * 2], s1 = slots[t * 2 + 1];
  const float w0 = comb_w[t * 2], w1 = comb_w[t * 2 + 1];
  const uint4 E0 = ((const uint4*)(eyb + (size_t)s0 * DIM))[lane];
  const uint4 E1 = ((const uint4*)(eyb + (size_t)s1 * DIM))[lane];
  const float4 sa = ((const float4*)(shb + (size_t)t * DIM))[lane * 2];
  const float4 sb = ((const float4*)(shb + (size_t)t * DIM))[lane * 2 + 1];
  const unsigned int e0[4] = {E0.x, E0.y, E0.z, E0.w};
  const unsigned int e1[4] = {E1.x, E1.y, E1.z, E1.w};
  const float shv[8] = {sa.x, sa.y, sa.z, sa.w, sb.x, sb.y, sb.z, sb.w};
  float m[8];
#pragma unroll
  for (int j = 0; j < 4; ++j) {
    m[2*j]   = w0 * b2f((unsigned short)(e0[j] & 0xffff)) + w1 * b2f((unsigned short)(e1[j] & 0xffff)) + shv[2*j];
    m[2*j+1] = w0 * b2f((unsigned short)(e0[j] >> 16))    + w1 * b2f((unsigned short)(e1[j] >> 16))    + shv[2*j+1];
  }
  float4* mo = (float4*)(moe + (size_t)t * DIM);
  mo[lane * 2]     = make_float4(m[0], m[1], m[2], m[3]);
  mo[lane * 2 + 1] = make_float4(m[4], m[5], m[6], m[7]);
  float s = 0.f;
#pragma unroll
  for (int j = 0; j < 8; ++j) s += m[j];
#pragma unroll
  for (int o = 32; o; o >>= 1) s += __shfl_xor(s, o, 64);
  const float mu = s * (1.f / DIM);
  float q = 0.f;
#pragma unroll
  for (int j = 0; j < 8; ++j) { const float d = m[j] - mu; q += d * d; }
#pragma unroll
  for (int o = 32; o; o >>= 1) q += __shfl_xor(q, o, 64);
  const float rs = rsqrtf(q * (1.f / DIM) + 1e-5f);
  const float4 ga = ((const float4*)g)[lane * 2], gb4 = ((const float4*)g)[lane * 2 + 1];
  const float4 ba = ((const float4*)b)[lane * 2], bb4 = ((const float4*)b)[lane * 2 + 1];
  const float gv[8] = {ga.x, ga.y, ga.z, ga.w, gb4.x, gb4.y, gb4.z, gb4.w};
  const float bv[8] = {ba.x, ba.y, ba.z, ba.w, bb4.x, bb4.y, bb4.z, bb4.w};
  ushort4 o0, o1;
  o0.x = f2b((m[0]-mu)*rs*gv[0]+bv[0]); o0.y = f2b((m[1]-mu)*rs*gv[1]+bv[1]);
  o0.z = f2b((m[2]-mu)*rs*gv[2]+bv[2]); o0.w = f2b((m[3]-mu)*rs*gv[3]+bv[3]);
  o1.x = f2b((m[4]-mu)*rs*gv[4]+bv[4]); o1.y = f2b((m[5]-mu)*rs*gv[5]+bv[5]);
  o1.z = f2b((m[6]-mu)*rs*gv[6]+bv[6]); o1.w = f2b((m[7]-mu)*rs*gv[7]+bv[7]);
  ((ushort4*)(fhb + (size_t)t * DIM))[lane * 2]     = o0;
  ((ushort4*)(fhb + (size_t)t * DIM))[lane * 2 + 1] = o1;
}

// ---------------- bf16 MFMA GEMM body, BMx128x32 tile (BM=128 or 64) ----------------
// MODE 0: outA = silu(acc+bias) bf16 | MODE 1: outA = acc+bias bf16
// MODE 2: outp = 0.25*(acc+bias) fp32 | MODE 3: outp = xres + mix + (acc+bias)
template <int MODE, bool EXPERT, int BM>
__device__ __forceinline__ void gemm_body(
    const unsigned short* __restrict__ A, int lda,
    const unsigned short* __restrict__ BT, const float* __restrict__ bias,
    int K, int N, int row0, int expert, int bn,
    const int* __restrict__ token_list,
    unsigned short* __restrict__ outA, const float* __restrict__ mix,
    const float* __restrict__ xres, float* __restrict__ outp,
    unsigned short* As, unsigned short* Bs) {
  const int tid = threadIdx.x;
  const unsigned short* Bt = BT + (size_t)expert * N * K + (size_t)bn * 128 * K;
  const float* bp = bias + (EXPERT ? expert * N : 0) + bn * 128;

  const int MA = BM / 64;            // A sub-blocks of 64 rows (2 or 1)
  const int r_a = tid >> 2;
  const int c8 = ((((tid & 3) - (tid >> 3)) & 3)) << 3;
  const unsigned short* arow0; const unsigned short* arow1 = nullptr;
  if (EXPERT && MODE == 0) {
    int t0 = token_list[row0 + r_a];       if (t0 < 0) t0 = 0;
    arow0 = A + (size_t)t0 * lda + c8;
    if (MA == 2) {
      int t1 = token_list[row0 + r_a + 64];  if (t1 < 0) t1 = 0;
      arow1 = A + (size_t)t1 * lda + c8;
    }
  } else {
    arow0 = A + (size_t)(row0 + r_a) * lda + c8;
    if (MA == 2) arow1 = A + (size_t)(row0 + r_a + 64) * lda + c8;
  }
  const unsigned short* brow0 = Bt + (size_t)r_a * K + c8;
  const unsigned short* brow1 = Bt + (size_t)(r_a + 64) * K + c8;

  const int lane = tid & 63, wid = tid >> 6;
  const int wm = wid & 1, wn = wid >> 1;
  const int l15 = lane & 15, qd = lane >> 4;
  const int WR = BM / 2;             // rows per wave-m (64 or 32)
  const int NA = WR / 16;            // a-tiles per wave (4 or 2)

  char* asb0 = (char*)As + wid * 1024;
  char* asb1 = (char*)As + 4096 + wid * 1024;
  char* bsb0 = (char*)Bs + wid * 1024;
  char* bsb1 = (char*)Bs + 4096 + wid * 1024;

  f32x4 acc[NA][4] = {};
  const int rdsw = ((qd + (l15 >> 1)) & 3) * 8;
  const bf16x8* afp = (const bf16x8*)&As[(wm * WR + l15) * 32 + rdsw];
  const bf16x8* bfp = (const bf16x8*)&Bs[(wn * 64 + l15) * 32 + rdsw];

  for (int k0 = 0; k0 < K; k0 += 32) {
    __syncthreads();
    async16(asb0, arow0 + k0);
    if (MA == 2) async16(asb1, arow1 + k0);
    async16(bsb0, brow0 + k0);
    async16(bsb1, brow1 + k0);
    __syncthreads();
    bf16x8 af[NA], bq[4];
#pragma unroll
    for (int a = 0; a < NA; ++a) af[a] = afp[a * 64];
#pragma unroll
    for (int b2 = 0; b2 < 4; ++b2) bq[b2] = bfp[b2 * 64];
#pragma unroll
    for (int a = 0; a < NA; ++a)
#pragma unroll
      for (int b2 = 0; b2 < 4; ++b2)
        acc[a][b2] = __builtin_amdgcn_mfma_f32_16x16x32_bf16(af[a], bq[b2], acc[a][b2], 0, 0, 0);
  }

  const int mloc = wm * WR + qd * 4;
  const int nloc = wn * 64 + l15;
#pragma unroll
  for (int b2 = 0; b2 < 4; ++b2) {
    const int n = bn * 128 + nloc + b2 * 16;
    const float bv = bp[nloc + b2 * 16];
#pragma unroll
    for (int a = 0; a < NA; ++a) {
#pragma unroll
      for (int r = 0; r < 4; ++r) {
        const int m = mloc + a * 16 + r;
        const float val = acc[a][b2][r] + bv;
        if (MODE == 0) {
          const float sg = val / (1.f + __expf(-val));
          outA[(size_t)(row0 + m) * N + n] = f2b(sg);
        } else if (MODE == 1) {
          outA[(size_t)(row0 + m) * N + n] = f2b(val);
        } else if (MODE == 2) {
          outp[(size_t)(row0 + m) * DIM + n] = 0.25f * val;
        } else {
          const size_t o = (size_t)(row0 + m) * DIM + n;
          outp[o] = xres[o] + mix[o] + val;
        }
      }
    }
  }
}

// ---- fused pair 1: expert GEMM1 (1280 blocks) + shared GEMM1 (256 blocks), BM=128 ----
__global__ __launch_bounds__(256) void gemm_g1(
    const unsigned short* __restrict__ hb,
    const unsigned short* __restrict__ ew1T, const float* __restrict__ eb1,
    const unsigned short* __restrict__ sw1T, const float* __restrict__ sb1,
    const int* __restrict__ tiledesc, const int* __restrict__ token_list,
    unsigned short* __restrict__ Abuf, unsigned short* __restrict__ Sbuf) {
  __shared__ unsigned short As[128 * 32];
  __shared__ unsigned short Bs[128 * 32];
  const int id = blockIdx.x;
  if (id < MAXTILES * 16) {
    const int by = id >> 4, bn = id & 15;
    const int expert = tiledesc[by * 2];
    if (expert < 0) return;
    const int row0 = tiledesc[by * 2 + 1];
    gemm_body<0, true, 128>(hb, DIM, ew1T, eb1, DIM, DHID, row0, expert, bn,
                            token_list, Abuf, nullptr, nullptr, nullptr, As, Bs);
  } else {
    const int id2 = id - MAXTILES * 16;
    const int by = id2 >> 3, bn = id2 & 7;
    gemm_body<0, false, 128>(hb, DIM, sw1T, sb1, DIM, DSH, by * 128, 0, bn,
                             nullptr, Sbuf, nullptr, nullptr, nullptr, As, Bs);
  }
}

// ---- fused pair 2: expert GEMM2 (640 blocks) + shared GEMM2 (256 blocks), BM=64 ----
__global__ __launch_bounds__(256) void gemm_g2(
    const unsigned short* __restrict__ Abuf,
    const unsigned short* __restrict__ ew2T, const float* __restrict__ eb2,
    const unsigned short* __restrict__ Sbuf,
    const unsigned short* __restrict__ sw2T, const float* __restrict__ sb2,
    const int* __restrict__ tiledesc,
    unsigned short* __restrict__ eyb, float* __restrict__ shb) {
  __shared__ unsigned short As[64 * 32];
  __shared__ unsigned short Bs[128 * 32];
  const int id = blockIdx.x;
  if (id < MAXTILES * 8) {
    const int seg = id >> 3, sub = (id >> 2) & 1, bn = id & 3;
    const int expert = tiledesc[seg * 2];
    if (expert < 0) return;
    const int row0 = tiledesc[seg * 2 + 1] + sub * 64;
    gemm_body<1, true, 64>(Abuf, DHID, ew2T, eb2, DHID, DIM, row0, expert, bn,
                           nullptr, eyb, nullptr, nullptr, nullptr, As, Bs);
  } else {
    const int id2 = id - MAXTILES * 8;
    const int by = id2 >> 2, bn = id2 & 3;
    gemm_body<2, false, 64>(Sbuf, DSH, sw2T, sb2, DSH, DIM, by * 64, 0, bn,
                            nullptr, nullptr, nullptr, nullptr, shb, As, Bs);
  }
}

// ---- standalone GEMMs for the final ff block ----
__global__ __launch_bounds__(256) void gemm_ff1(
    const unsigned short* __restrict__ A,
    const unsigned short* __restrict__ BT, const float* __restrict__ bias,
    unsigned short* __restrict__ outA) {
  __shared__ unsigned short As[128 * 32];
  __shared__ unsigned short Bs[128 * 32];
  gemm_body<0, false, 128>(A, DIM, BT, bias, DIM, DHID, blockIdx.y * 128, 0, blockIdx.x,
                           nullptr, outA, nullptr, nullptr, nullptr, As, Bs);
}
__global__ __launch_bounds__(256) void gemm_ff2(
    const unsigned short* __restrict__ A,
    const unsigned short* __restrict__ BT, const float* __restrict__ bias,
    const float* __restrict__ mix, const float* __restrict__ xres,
    float* __restrict__ outp) {
  __shared__ unsigned short As[64 * 32];
  __shared__ unsigned short Bs[128 * 32];
  gemm_body<3, false, 64>(A, DHID, BT, bias, DHID, DIM, blockIdx.y * 64, 0, blockIdx.x,
                          nullptr, nullptr, mix, xres, outp, As, Bs);
}

extern "C" void kernel_launch(void* const* d_in, const int* in_sizes, int n_in,
                              void* d_out, int out_size, void* d_ws, size_t ws_size,
                              hipStream_t stream) {
  (void)in_sizes; (void)n_in; (void)out_size; (void)ws_size;
  const float* x    = (const float*)d_in[0];
  const float* lng  = (const float*)d_in[1];
  const float* lnb  = (const float*)d_in[2];
  const float* rw   = (const float*)d_in[3];
  const float* rb   = (const float*)d_in[4];
  const float* ew1  = (const float*)d_in[5];
  const float* eb1  = (const float*)d_in[6];
  const float* ew2  = (const float*)d_in[7];
  const float* eb2  = (const float*)d_in[8];
  const float* sw1  = (const float*)d_in[9];
  const float* sb1  = (const float*)d_in[10];
  const float* sw2  = (const float*)d_in[11];
  const float* sb2  = (const float*)d_in[12];
  const float* flng = (const float*)d_in[13];
  const float* flnb = (const float*)d_in[14];
  const float* fw1  = (const float*)d_in[15];
  const float* fb1  = (const float*)d_in[16];
  const float* fw2  = (const float*)d_in[17];
  const float* fb2  = (const float*)d_in[18];
  float* out = (float*)d_out;

  char* ws = (char*)d_ws;
  size_t off = 0;
  auto alloc = [&](size_t bytes) -> void* {
    void* p = ws + off;
    off += (bytes + 255) & ~(size_t)255;
    return p;
  };
  unsigned short* ew1T = (unsigned short*)alloc((size_t)NEXP * DIM * DHID * 2);
  unsigned short* ew2T = (unsigned short*)alloc((size_t)NEXP * DHID * DIM * 2);
  unsigned short* sw1T = (unsigned short*)alloc((size_t)DIM * DSH * 2);
  unsigned short* sw2T = (unsigned short*)alloc((size_t)DSH * DIM * 2);
  unsigned short* fw1T = (unsigned short*)alloc((size_t)DIM * DHID * 2);
  unsigned short* fw2T = (unsigned short*)alloc((size_t)DHID * DIM * 2);
  unsigned short* hb   = (unsigned short*)alloc((size_t)T_TOK * DIM * 2);
  unsigned short* fhb  = (unsigned short*)alloc((size_t)T_TOK * DIM * 2);
  unsigned short* Abuf = (unsigned short*)alloc((size_t)ROWSCAP * DHID * 2);
  unsigned short* Sbuf = (unsigned short*)alloc((size_t)T_TOK * DSH * 2);
  unsigned short* eyb  = (unsigned short*)alloc((size_t)ROWSCAP * DIM * 2);
  float* shb = (float*)alloc((size_t)T_TOK * DIM * 4);
  float* moe = (float*)alloc((size_t)T_TOK * DIM * 4);
  int*   comb_idx = (int*)alloc((size_t)T_TOK * 2 * 4);
  float* comb_w   = (float*)alloc((size_t)T_TOK * 2 * 4);
  int*   slots    = (int*)alloc((size_t)T_TOK * 2 * 4);
  int* counts   = (int*)alloc(64);
  int* offs     = (int*)alloc(64);
  int* fill     = (int*)alloc(64);
  int* tiledesc = (int*)alloc(MAXTILES * 2 * 4);
  int* token_list = (int*)alloc((size_t)ROWSCAP * 4);

  hipMemsetAsync(counts, 0, 64, stream);
  hipMemsetAsync(token_list, 0xFF, (size_t)ROWSCAP * 4, stream);  // -1

  // transposes (8960 blocks) + LN/router (1024 blocks) in one dispatch
  prep_kernel<<<9984, 256, 0, stream>>>(x, lng, lnb, rw, rb, hb, comb_idx, comb_w, counts,
                                        ew1, ew2, sw1, sw2, fw1, fw2,
                                        ew1T, ew2T, sw1T, sw2T, fw1T, fw2T);
  plan_kernel<<<1, 64, 0, stream>>>(counts, offs, fill, tiledesc);
  scatter_kernel<<<T_TOK / 256, 256, 0, stream>>>(comb_idx, comb_w, offs, fill, token_list, slots);

  // expert G1 + shared G1 (BM=128)
  gemm_g1<<<MAXTILES * 16 + 256, 256, 0, stream>>>(hb, ew1T, eb1, sw1T, sb1,
                                                   tiledesc, token_list, Abuf, Sbuf);
  // expert G2 + shared G2 (BM=64: 2x blocks for occupancy on N=512)
  gemm_g2<<<MAXTILES * 8 + 256, 256, 0, stream>>>(Abuf, ew2T, eb2, Sbuf, sw2T, sb2,
                                                  tiledesc, eyb, shb);
  combine_ln_kernel<<<T_TOK / 4, 256, 0, stream>>>(eyb, shb, slots, comb_w, flng, flnb, moe, fhb);
  gemm_ff1<<<dim3(DHID / 128, T_TOK / 128), 256, 0, stream>>>(fhb, fw1T, fb1, Abuf);
  gemm_ff2<<<dim3(DIM / 128, T_TOK / 64), 256, 0, stream>>>(Abuf, fw2T, fb2, moe, x, out);
}